// Round 5
// baseline (304.442 us; speedup 1.0000x reference)
//
#include <hip/hip_runtime.h>

// GCN: 3x GCNConv(64->64) + global_mean_pool + linear(64->2)
// N=100000 nodes, E=1.6M edges, 64 graphs.
// Round 19 (resubmit; container infra failure last round): base = r17.
//   NEW: 4-row interleaved gather. Each wave's 4 rows are gathered in ONE
//   quad-loop issuing 4 independent loads/iteration (one per row) into
//   per-row f32 accumulators; all shuffle-reduces/epilogues deferred until
//   after the loop. Raises loads-in-flight ~4x in the latency-bound gather.
//   Accumulation: direct f32 (more precise than r17's f16 tree).
// Rest (f16 buffers, fused pool 16-row blocks, prep'd f16 weights) = r17.

#define NF 64
#define ELLW 64
#define BINSHIFT 9
#define BINW 512
#define NB 196         // ceil(100000 / 512)
#define BINCAP 9216    // per-bin edge cap: mean 8163 + ~11 sigma
#define LPITCH 68      // ushort pitch for C-repack LDS tile

typedef __attribute__((ext_vector_type(8))) _Float16 f16x8;  // 8 f16 (4 VGPRs)
typedef __attribute__((ext_vector_type(4))) _Float16 f16x4;  // 4 f16 (2 VGPRs)
typedef __attribute__((ext_vector_type(4))) float f32x4;     // 4 fp32 acc

__device__ inline unsigned short f2h_u(float f) {
    return __builtin_bit_cast(unsigned short, (_Float16)f);   // v_cvt_f16_f32 (RNE)
}
__device__ inline unsigned int pack_h2(float a, float b) {
    unsigned int ua = f2h_u(a), ub = f2h_u(b);
    return ua | (ub << 16);
}

// Phase A: partition edges by dst bin (LDS histogram, contiguous appends).
// Record = src | (dstLocal << 17): src < 2^17 (n=100000), dstLocal < 512.
__global__ void binA_kernel(const int* __restrict__ src, const int* __restrict__ dst,
                            int* __restrict__ binCnt, int* __restrict__ binEdges,
                            int nE, int chunk) {
    __shared__ int hist[NB];
    __shared__ int base[NB];
    int t = threadIdx.x;
    if (t < NB) hist[t] = 0;
    __syncthreads();
    int e0 = blockIdx.x * chunk;
    int e1 = min(e0 + chunk, nE);
    for (int e = e0 + t; e < e1; e += blockDim.x) {
        int b = dst[e] >> BINSHIFT;
        atomicAdd(&hist[b], 1);
    }
    __syncthreads();
    if (t < NB) {
        base[t] = atomicAdd(&binCnt[t], hist[t]);
        hist[t] = 0;
    }
    __syncthreads();
    for (int e = e0 + t; e < e1; e += blockDim.x) {
        int d = dst[e];
        int b = d >> BINSHIFT;
        int pos = base[b] + atomicAdd(&hist[b], 1);
        if (pos < BINCAP)
            binEdges[(size_t)b * BINCAP + pos] = src[e] | ((d & (BINW - 1)) << 17);
    }
}

// Phase B: one block per bin; LDS counters. ELL slot 0 = self edge; rows padded
// to multiple of 4 with dummy index n (h'[n] = 0 => zero contribution).
// Block 0 also zeroes the dummy feature rows of both ping-pong buffers.
__global__ void __launch_bounds__(512) binB_kernel(const int* __restrict__ binEdges,
                            const int* __restrict__ binCnt, int* __restrict__ cnt,
                            float* __restrict__ dinv, int* __restrict__ colELL, int n,
                            unsigned int* __restrict__ dummyA, unsigned int* __restrict__ dummyB) {
    __shared__ int lcnt[BINW];
    int t = threadIdx.x;
    int b = blockIdx.x;
    if (b == 0 && t < 32) { dummyA[t] = 0u; dummyB[t] = 0u; }   // h'[n] = 0 (128B each)
    for (int i = t; i < BINW; i += blockDim.x) lcnt[i] = 1;   // slot 0 = self
    __syncthreads();
    int m = binCnt[b];
    if (m > BINCAP) m = BINCAP;
    const int* be = binEdges + (size_t)b * BINCAP;
    int nbase = b << BINSHIFT;
    for (int e = t; e < m; e += blockDim.x) {
        int v = be[e];
        int s = v & 0x1FFFF;
        int dl = v >> 17;
        int pos = atomicAdd(&lcnt[dl], 1);
        if (pos < ELLW) colELL[(size_t)(nbase + dl) * ELLW + pos] = s;
    }
    __syncthreads();
    for (int i = t; i < BINW; i += blockDim.x) {
        int node = nbase + i;
        if (node < n) {
            int c = lcnt[i];
            if (c > ELLW) c = ELLW;
            colELL[(size_t)node * ELLW + 0] = node;        // self edge
            int cpad = (c + 3) & ~3;
            for (int j = c; j < cpad; ++j)
                colELL[(size_t)node * ELLW + j] = n;       // dummy (h'[n] = 0)
            cnt[node] = c;                                  // deg+1
            dinv[node] = rsqrtf((float)c);
        }
    }
}

// One-time f32 -> f16 conversion of the three 64x64 weight matrices.
__global__ void prep_kernel(const float* __restrict__ W1, const float* __restrict__ W2,
                            const float* __restrict__ W3, unsigned short* __restrict__ w1h,
                            unsigned short* __restrict__ w2h, unsigned short* __restrict__ w3h) {
    int t = blockIdx.x * blockDim.x + threadIdx.x;
    if (t < NF * NF) {
        w1h[t] = f2h_u(W1[t]);
        w2h[t] = f2h_u(W2[t]);
        w3h[t] = f2h_u(W3[t]);
    }
}

// ---- layer-1 MFMA GEMM: bufA = dinv * (x @ W1), f16 out via LDS repack ----
__device__ inline void load_W_frags(const unsigned short* __restrict__ Wh, int r16, int kq,
                                    f16x8 bfr[4][2]) {
#pragma unroll
    for (int nt = 0; nt < 4; ++nt)
#pragma unroll
        for (int kh = 0; kh < 2; ++kh) {
            f16x8 f;
#pragma unroll
            for (int j = 0; j < 8; ++j)
                f[j] = __builtin_bit_cast(_Float16,
                        Wh[(kh * 32 + kq * 8 + j) * NF + nt * 16 + r16]);
            bfr[nt][kh] = f;
        }
}

__global__ void __launch_bounds__(256) gemm1_mfma_kernel(const float* __restrict__ A,
                                                         const unsigned short* __restrict__ Wh,
                                                         const float* __restrict__ dinv,
                                                         unsigned short* __restrict__ outB, int n) {
    __shared__ unsigned short T[4][16 * LPITCH];
    int lane = threadIdx.x & 63;
    int r16 = lane & 15, kq = lane >> 4;
    int wv = threadIdx.x >> 6;
    int wid = blockIdx.x * 4 + wv;
    int nw = gridDim.x * 4;
    f16x8 bfr[4][2];
    load_W_frags(Wh, r16, kq, bfr);
    int ntiles = n >> 4;
    for (int t = wid; t < ntiles; t += nw) {
        int r0 = t << 4;
        const float* ar = A + (size_t)(r0 + r16) * NF + kq * 8;
        f16x8 a0, a1;
        float4 v0 = *(const float4*)(ar);
        float4 v1 = *(const float4*)(ar + 4);
        float4 v2 = *(const float4*)(ar + 32);
        float4 v3 = *(const float4*)(ar + 36);
        a0[0] = (_Float16)v0.x; a0[1] = (_Float16)v0.y;
        a0[2] = (_Float16)v0.z; a0[3] = (_Float16)v0.w;
        a0[4] = (_Float16)v1.x; a0[5] = (_Float16)v1.y;
        a0[6] = (_Float16)v1.z; a0[7] = (_Float16)v1.w;
        a1[0] = (_Float16)v2.x; a1[1] = (_Float16)v2.y;
        a1[2] = (_Float16)v2.z; a1[3] = (_Float16)v2.w;
        a1[4] = (_Float16)v3.x; a1[5] = (_Float16)v3.y;
        a1[6] = (_Float16)v3.z; a1[7] = (_Float16)v3.w;
        f32x4 acc[4];
#pragma unroll
        for (int nt = 0; nt < 4; ++nt) {
            acc[nt] = (f32x4)(0.0f);
            acc[nt] = __builtin_amdgcn_mfma_f32_16x16x32_f16(a0, bfr[nt][0], acc[nt], 0, 0, 0);
            acc[nt] = __builtin_amdgcn_mfma_f32_16x16x32_f16(a1, bfr[nt][1], acc[nt], 0, 0, 0);
        }
        float ds[4];
#pragma unroll
        for (int reg = 0; reg < 4; ++reg) ds[reg] = dinv[r0 + kq * 4 + reg];
        unsigned short* Tw = T[wv];
#pragma unroll
        for (int nt = 0; nt < 4; ++nt)
#pragma unroll
            for (int reg = 0; reg < 4; ++reg)
                Tw[(kq * 4 + reg) * LPITCH + nt * 16 + r16] = f2h_u(acc[nt][reg] * ds[reg]);
#pragma unroll
        for (int it = 0; it < 4; ++it) {
            int row = it * 4 + kq;
            uint2 v = *(const uint2*)&Tw[row * LPITCH + r16 * 4];
            *(uint2*)(outB + (size_t)(r0 + row) * NF + r16 * 4) = v;
        }
    }
}

// ---- fused: h = relu(dinv[d]*sum h'[s] + bias); out = dinv * (h @ W) ----
// Block = 16 rows. First 32 ELL columns per row staged in LDS. The wave's
// 4 rows are gathered in ONE interleaved quad-loop (4 independent loads in
// flight per iteration); shuffle-reduces deferred to after the loop.
__global__ void __launch_bounds__(256) fused_agg_gemm_kernel(
        const unsigned short* __restrict__ hB, const int* __restrict__ colELL,
        const int* __restrict__ cnt, const float* __restrict__ dinv,
        const float* __restrict__ bias, const unsigned short* __restrict__ Wh,
        unsigned short* __restrict__ outB, int n) {
    __shared__ int Icol[16 * 32];                 // 2KB: first 32 cols of 16 rows
    __shared__ int Icnt[16];
    __shared__ unsigned short Tin[2048];          // 16 rows x 64 feats, A-frag order
    __shared__ unsigned short Tout[16 * LPITCH];  // C repack
    int lane = threadIdx.x & 63;
    int wv = threadIdx.x >> 6;
    int es = lane >> 4, fq = lane & 15;
    int r16 = lane & 15, kq = lane >> 4;
    int r0 = blockIdx.x << 4;
    // stage first 32 cols: 512 ints = 128 int4 (8 per row, 128B contiguous runs)
    if (threadIdx.x < 128) {
        int srow = threadIdx.x >> 3, sj = threadIdx.x & 7;
        ((int4*)Icol)[srow * 8 + sj] =
            *(const int4*)(colELL + (size_t)(r0 + srow) * ELLW + sj * 4);
    } else if (threadIdx.x < 144) {
        Icnt[threadIdx.x - 128] = cnt[r0 + threadIdx.x - 128];
    }
    f16x8 bfr0, bfr1;
    {
        f16x8 f0, f1;
#pragma unroll
        for (int j = 0; j < 8; ++j) {
            f0[j] = __builtin_bit_cast(_Float16, Wh[(kq * 8 + j) * NF + wv * 16 + r16]);
            f1[j] = __builtin_bit_cast(_Float16, Wh[(32 + kq * 8 + j) * NF + wv * 16 + r16]);
        }
        bfr0 = f0; bfr1 = f1;
    }
    __syncthreads();
    // ---- interleaved 4-row gather ----
    int nqr[4]; const int* crp[4];
    float ac[4][4];
#pragma unroll
    for (int rr = 0; rr < 4; ++rr) {
        int lrow = wv * 4 + rr;
        int c = Icnt[lrow];
        int cl = c < 32 ? c : 32;
        nqr[rr] = (cl + 3) >> 2;
        crp[rr] = Icol + lrow * 32;
#pragma unroll
        for (int k = 0; k < 4; ++k) ac[rr][k] = 0.f;
    }
    int nqmax = max(max(nqr[0], nqr[1]), max(nqr[2], nqr[3]));
    for (int q = 0; q < nqmax; ++q) {
#pragma unroll
        for (int rr = 0; rr < 4; ++rr) {
            if (q < nqr[rr]) {
                int s = crp[rr][q * 4 + es];
                f16x4 h = __builtin_bit_cast(f16x4,
                        *(const uint2*)(hB + (size_t)s * NF + fq * 4));
                ac[rr][0] += (float)h[0]; ac[rr][1] += (float)h[1];
                ac[rr][2] += (float)h[2]; ac[rr][3] += (float)h[3];
            }
        }
    }
#pragma unroll
    for (int rr = 0; rr < 4; ++rr) {      // rare tall rows (~1.5e-4)
        int lrow = wv * 4 + rr;
        int c = Icnt[lrow];
        if (c > 32) {
            int nq = (c + 3) >> 2;
            const int* crg = colELL + (size_t)(r0 + lrow) * ELLW;
            for (int qq = 8; qq < nq; ++qq) {
                int sg = crg[qq * 4 + es];
                f16x4 hg = __builtin_bit_cast(f16x4,
                        *(const uint2*)(hB + (size_t)sg * NF + fq * 4));
                ac[rr][0] += (float)hg[0]; ac[rr][1] += (float)hg[1];
                ac[rr][2] += (float)hg[2]; ac[rr][3] += (float)hg[3];
            }
        }
    }
    // ---- per-row reduce + epilogue ----
#pragma unroll
    for (int rr = 0; rr < 4; ++rr) {
        int row = r0 + wv * 4 + rr;
        float a0 = ac[rr][0], a1 = ac[rr][1], a2 = ac[rr][2], a3 = ac[rr][3];
        a0 += __shfl_xor(a0, 16); a1 += __shfl_xor(a1, 16);
        a2 += __shfl_xor(a2, 16); a3 += __shfl_xor(a3, 16);
        a0 += __shfl_xor(a0, 32); a1 += __shfl_xor(a1, 32);
        a2 += __shfl_xor(a2, 32); a3 += __shfl_xor(a3, 32);
        if (es == 0) {
            float dd = dinv[row];
            float4 b4 = *(const float4*)(bias + fq * 4);
            a0 = fmaxf(dd * a0 + b4.x, 0.f); a1 = fmaxf(dd * a1 + b4.y, 0.f);
            a2 = fmaxf(dd * a2 + b4.z, 0.f); a3 = fmaxf(dd * a3 + b4.w, 0.f);
            uint2 v;
            v.x = pack_h2(a0, a1);
            v.y = pack_h2(a2, a3);
            int ibase = ((fq >> 3) << 10) + (((fq >> 1) & 3) << 7)
                      + (wv * 4 + rr) * 8 + ((fq & 1) << 2);
            *(uint2*)&Tin[ibase] = v;
        }
    }
    __syncthreads();
    f16x8 A0 = *(const f16x8*)&Tin[lane * 8];
    f16x8 A1 = *(const f16x8*)&Tin[1024 + lane * 8];
    f32x4 acc = (f32x4)(0.0f);
    acc = __builtin_amdgcn_mfma_f32_16x16x32_f16(A0, bfr0, acc, 0, 0, 0);
    acc = __builtin_amdgcn_mfma_f32_16x16x32_f16(A1, bfr1, acc, 0, 0, 0);
    float ds[4];
#pragma unroll
    for (int reg = 0; reg < 4; ++reg) ds[reg] = dinv[r0 + kq * 4 + reg];
#pragma unroll
    for (int reg = 0; reg < 4; ++reg)
        Tout[(kq * 4 + reg) * LPITCH + wv * 16 + r16] = f2h_u(acc[reg] * ds[reg]);
    __syncthreads();
    int t = threadIdx.x;
    int orow = t >> 4, ocq = t & 15;
    uint2 v = *(const uint2*)&Tout[orow * LPITCH + ocq * 4];
    *(uint2*)(outB + (size_t)(r0 + orow) * NF + ocq * 4) = v;
}

// ---- layer-3 aggregation fused with mean-pool accumulation ----
// 16-row blocks (r17 structure) + interleaved 4-row gather.
__global__ void __launch_bounds__(256) gather3_pool_kernel(
        const unsigned short* __restrict__ hB, const int* __restrict__ colELL,
        const int* __restrict__ cnt, const float* __restrict__ dinv,
        const float* __restrict__ bias, const int* __restrict__ batch,
        float* __restrict__ pooled, int n) {
    __shared__ int Icol[16 * 32];
    __shared__ int Icnt[16];
    __shared__ float PL[2][NF];
    int lane = threadIdx.x & 63;
    int wv = threadIdx.x >> 6;
    int es = lane >> 4, fq = lane & 15;
    int r0 = blockIdx.x << 4;
    if (threadIdx.x < 128) {
        int srow = threadIdx.x >> 3, sj = threadIdx.x & 7;
        ((int4*)Icol)[srow * 8 + sj] =
            *(const int4*)(colELL + (size_t)(r0 + srow) * ELLW + sj * 4);
        PL[threadIdx.x >> 6][threadIdx.x & 63] = 0.f;
    } else if (threadIdx.x < 144) {
        Icnt[threadIdx.x - 128] = cnt[r0 + threadIdx.x - 128];
    }
    __syncthreads();
    int gb = batch[r0];
    float4 b4 = *(const float4*)(bias + fq * 4);
    // ---- interleaved 4-row gather ----
    int nqr[4]; const int* crp[4];
    float ac[4][4];
#pragma unroll
    for (int rr = 0; rr < 4; ++rr) {
        int lrow = wv * 4 + rr;
        int c = Icnt[lrow];
        int cl = c < 32 ? c : 32;
        nqr[rr] = (cl + 3) >> 2;
        crp[rr] = Icol + lrow * 32;
#pragma unroll
        for (int k = 0; k < 4; ++k) ac[rr][k] = 0.f;
    }
    int nqmax = max(max(nqr[0], nqr[1]), max(nqr[2], nqr[3]));
    for (int q = 0; q < nqmax; ++q) {
#pragma unroll
        for (int rr = 0; rr < 4; ++rr) {
            if (q < nqr[rr]) {
                int s = crp[rr][q * 4 + es];
                f16x4 h = __builtin_bit_cast(f16x4,
                        *(const uint2*)(hB + (size_t)s * NF + fq * 4));
                ac[rr][0] += (float)h[0]; ac[rr][1] += (float)h[1];
                ac[rr][2] += (float)h[2]; ac[rr][3] += (float)h[3];
            }
        }
    }
#pragma unroll
    for (int rr = 0; rr < 4; ++rr) {      // rare tall rows
        int lrow = wv * 4 + rr;
        int c = Icnt[lrow];
        if (c > 32) {
            int nq = (c + 3) >> 2;
            const int* crg = colELL + (size_t)(r0 + lrow) * ELLW;
            for (int qq = 8; qq < nq; ++qq) {
                int sg = crg[qq * 4 + es];
                f16x4 hg = __builtin_bit_cast(f16x4,
                        *(const uint2*)(hB + (size_t)sg * NF + fq * 4));
                ac[rr][0] += (float)hg[0]; ac[rr][1] += (float)hg[1];
                ac[rr][2] += (float)hg[2]; ac[rr][3] += (float)hg[3];
            }
        }
    }
    // ---- per-row reduce + pool accumulation ----
#pragma unroll
    for (int rr = 0; rr < 4; ++rr) {
        int row = r0 + wv * 4 + rr;
        float a0 = ac[rr][0], a1 = ac[rr][1], a2 = ac[rr][2], a3 = ac[rr][3];
        a0 += __shfl_xor(a0, 16); a1 += __shfl_xor(a1, 16);
        a2 += __shfl_xor(a2, 16); a3 += __shfl_xor(a3, 16);
        a0 += __shfl_xor(a0, 32); a1 += __shfl_xor(a1, 32);
        a2 += __shfl_xor(a2, 32); a3 += __shfl_xor(a3, 32);
        if (es == 0) {
            float dd = dinv[row];
            float r0f = dd * a0 + b4.x, r1f = dd * a1 + b4.y;
            float r2f = dd * a2 + b4.z, r3f = dd * a3 + b4.w;
            int g = batch[row];
            int sel = g - gb;
            if (sel < 2) {
                atomicAdd(&PL[sel][fq * 4 + 0], r0f);
                atomicAdd(&PL[sel][fq * 4 + 1], r1f);
                atomicAdd(&PL[sel][fq * 4 + 2], r2f);
                atomicAdd(&PL[sel][fq * 4 + 3], r3f);
            } else {    // tile spans >2 graphs: direct global accumulation
                atomicAdd(&pooled[g * NF + fq * 4 + 0], r0f);
                atomicAdd(&pooled[g * NF + fq * 4 + 1], r1f);
                atomicAdd(&pooled[g * NF + fq * 4 + 2], r2f);
                atomicAdd(&pooled[g * NF + fq * 4 + 3], r3f);
            }
        }
    }
    __syncthreads();
    if (threadIdx.x < 128) {
        int s = threadIdx.x >> 6, f = threadIdx.x & 63;
        float v = PL[s][f];
        if (v != 0.f) atomicAdd(&pooled[(gb + s) * NF + f], v);
    }
}

// counts[g] = #nodes in graph g (LDS histogram of batch)
__global__ void counts_kernel(const int* __restrict__ batch, float* __restrict__ counts, int n) {
    __shared__ int h[64];
    int t = threadIdx.x;
    if (t < 64) h[t] = 0;
    __syncthreads();
    for (int i = blockIdx.x * blockDim.x + t; i < n; i += gridDim.x * blockDim.x)
        atomicAdd(&h[batch[i]], 1);
    __syncthreads();
    if (t < 64 && h[t] > 0) atomicAdd(&counts[t], (float)h[t]);
}

// out[g][c] = (pooled[g][:]/max(cnt,1)) @ Wl[:,c] + bl[c]
__global__ void final_kernel(const float* __restrict__ pooled, const float* __restrict__ counts,
                             const float* __restrict__ Wl, const float* __restrict__ bl,
                             float* __restrict__ out) {
    int t = threadIdx.x;  // 128 threads: g = t>>1, c = t&1
    int g = t >> 1, c = t & 1;
    float inv = 1.0f / fmaxf(counts[g], 1.0f);
    float s = 0.0f;
#pragma unroll
    for (int j = 0; j < NF; ++j) s += pooled[g * NF + j] * Wl[j * 2 + c];
    out[t] = s * inv + bl[c];
}

extern "C" void kernel_launch(void* const* d_in, const int* in_sizes, int n_in,
                              void* d_out, int out_size, void* d_ws, size_t ws_size,
                              hipStream_t stream) {
    const float* x     = (const float*)d_in[0];
    const int*   ei    = (const int*)d_in[1];
    const int*   batch = (const int*)d_in[2];
    const float* W1    = (const float*)d_in[3];
    const float* b1    = (const float*)d_in[4];
    const float* W2    = (const float*)d_in[5];
    const float* b2    = (const float*)d_in[6];
    const float* W3    = (const float*)d_in[7];
    const float* b3    = (const float*)d_in[8];
    const float* Wl    = (const float*)d_in[9];
    const float* bl    = (const float*)d_in[10];
    float* out = (float*)d_out;

    const int n  = in_sizes[0] / NF;   // 100000 (divisible by 16)
    const int nE = in_sizes[1] / 2;    // 1600000
    const int* src = ei;
    const int* dst = ei + nE;

    // workspace layout (256B-aligned)
    char* ws = (char*)d_ws;
    auto alloc = [&](size_t bytes) {
        char* p = ws;
        ws += (bytes + 255) & ~(size_t)255;
        return p;
    };
    unsigned short* bufA = (unsigned short*)alloc((size_t)(n + 16) * NF * 2); // +dummy row
    unsigned short* bufB = (unsigned short*)alloc((size_t)(n + 16) * NF * 2);
    float* scratch = (float*)alloc((size_t)n * NF * 4);                  // binEdges alias
    int*   binEdges = (int*)scratch;                                     // build phase only (7.2 MB)
    int*   colELL = (int*)alloc((size_t)n * ELLW * 4);                   // 25.7 MB
    float* dinv   = (float*)alloc((size_t)(n + 16) * 4);                 // +dummy
    int*   cnt    = (int*)alloc((size_t)n * 4);
    unsigned short* w1h = (unsigned short*)alloc((size_t)NF * NF * 2);
    unsigned short* w2h = (unsigned short*)alloc((size_t)NF * NF * 2);
    unsigned short* w3h = (unsigned short*)alloc((size_t)NF * NF * 2);
    // zero-init tail: binCnt | pooled | counts (one memset)
    char*  ztail  = ws;
    int*   binCnt = (int*)alloc(NB * 4);
    float* pooled = (float*)alloc(64 * NF * 4);
    float* counts = (float*)alloc(64 * 4);
    size_t zbytes = (size_t)(ws - ztail);

    (void)hipMemsetAsync(ztail, 0, zbytes, stream);

    // ---- binned ELL build (once, reused by all 3 layers) ----
    const int chunk = 3200;
    binA_kernel<<<(nE + chunk - 1) / chunk, 256, 0, stream>>>(src, dst, binCnt, binEdges, nE, chunk);
    binB_kernel<<<NB, 512, 0, stream>>>(binEdges, binCnt, cnt, dinv, colELL, n,
                                        (unsigned int*)(bufA + (size_t)n * NF),
                                        (unsigned int*)(bufB + (size_t)n * NF));
    counts_kernel<<<98, 1024, 0, stream>>>(batch, counts, n);
    prep_kernel<<<16, 256, 0, stream>>>(W1, W2, W3, w1h, w2h, w3h);

    const int tile_grid = n >> 4;     // 6250 blocks of 16 rows

    // conv1 GEMM: bufA = dinv * (x @ W1)
    gemm1_mfma_kernel<<<1563, 256, 0, stream>>>(x, w1h, dinv, bufA, n);
    // fused conv1-agg + conv2 GEMM: bufB = dinv * (relu(AGG'(bufA)+b1) @ W2)
    fused_agg_gemm_kernel<<<tile_grid, 256, 0, stream>>>(bufA, colELL, cnt, dinv, b1, w2h, bufB, n);
    // fused conv2-agg + conv3 GEMM: bufA = dinv * (relu(AGG'(bufB)+b2) @ W3)
    fused_agg_gemm_kernel<<<tile_grid, 256, 0, stream>>>(bufB, colELL, cnt, dinv, b2, w3h, bufA, n);
    // conv3 aggregation + mean-pool accumulation (16-row blocks)
    gather3_pool_kernel<<<tile_grid, 256, 0, stream>>>(bufA, colELL, cnt, dinv, b3,
                                                       batch, pooled, n);

    final_kernel<<<1, 128, 0, stream>>>(pooled, counts, Wl, bl, out);
}

// Round 6
// 255.886 us; speedup vs baseline: 1.1898x; 1.1898x over previous
//
#include <hip/hip_runtime.h>

// GCN: 3x GCNConv(64->64) + global_mean_pool + linear(64->2)
// N=100000 nodes, E=1.6M edges, 64 graphs.
// Round 20: fused_agg reverted to exact r17 (r18/r19 gather restructures both
// regressed). gather3_pool switched to ROW-PARALLEL gather: wave = 8 rows x
// 8 feature-octets; each lane accumulates its row's 8 features (dwordx4
// loads). One load instr = 8 scattered rows (vs 4), unroll-4 = 32 lines in
// flight/wave (vs 16); no shuffle reduce, no divergent epilogue. 32 rows per
// block (grid 3125). fused_agg serves as in-run A/B control for the new
// gather shape.

#define NF 64
#define ELLW 64
#define BINSHIFT 9
#define BINW 512
#define NB 196         // ceil(100000 / 512)
#define BINCAP 9216    // per-bin edge cap: mean 8163 + ~11 sigma
#define LPITCH 68      // ushort pitch for C-repack LDS tile

typedef __attribute__((ext_vector_type(8))) _Float16 f16x8;  // 8 f16 (4 VGPRs)
typedef __attribute__((ext_vector_type(4))) _Float16 f16x4;  // 4 f16 (2 VGPRs)
typedef __attribute__((ext_vector_type(4))) float f32x4;     // 4 fp32 acc

__device__ inline unsigned short f2h_u(float f) {
    return __builtin_bit_cast(unsigned short, (_Float16)f);   // v_cvt_f16_f32 (RNE)
}
__device__ inline unsigned int pack_h2(float a, float b) {
    unsigned int ua = f2h_u(a), ub = f2h_u(b);
    return ua | (ub << 16);
}

// Phase A: partition edges by dst bin (LDS histogram, contiguous appends).
// Record = src | (dstLocal << 17): src < 2^17 (n=100000), dstLocal < 512.
__global__ void binA_kernel(const int* __restrict__ src, const int* __restrict__ dst,
                            int* __restrict__ binCnt, int* __restrict__ binEdges,
                            int nE, int chunk) {
    __shared__ int hist[NB];
    __shared__ int base[NB];
    int t = threadIdx.x;
    if (t < NB) hist[t] = 0;
    __syncthreads();
    int e0 = blockIdx.x * chunk;
    int e1 = min(e0 + chunk, nE);
    for (int e = e0 + t; e < e1; e += blockDim.x) {
        int b = dst[e] >> BINSHIFT;
        atomicAdd(&hist[b], 1);
    }
    __syncthreads();
    if (t < NB) {
        base[t] = atomicAdd(&binCnt[t], hist[t]);
        hist[t] = 0;
    }
    __syncthreads();
    for (int e = e0 + t; e < e1; e += blockDim.x) {
        int d = dst[e];
        int b = d >> BINSHIFT;
        int pos = base[b] + atomicAdd(&hist[b], 1);
        if (pos < BINCAP)
            binEdges[(size_t)b * BINCAP + pos] = src[e] | ((d & (BINW - 1)) << 17);
    }
}

// Phase B: one block per bin; LDS counters. ELL slot 0 = self edge; rows padded
// to multiple of 4 with dummy index n (h'[n] = 0 => zero contribution).
// Block 0 also zeroes the dummy feature rows of both ping-pong buffers.
__global__ void __launch_bounds__(512) binB_kernel(const int* __restrict__ binEdges,
                            const int* __restrict__ binCnt, int* __restrict__ cnt,
                            float* __restrict__ dinv, int* __restrict__ colELL, int n,
                            unsigned int* __restrict__ dummyA, unsigned int* __restrict__ dummyB) {
    __shared__ int lcnt[BINW];
    int t = threadIdx.x;
    int b = blockIdx.x;
    if (b == 0 && t < 32) { dummyA[t] = 0u; dummyB[t] = 0u; }   // h'[n] = 0 (128B each)
    for (int i = t; i < BINW; i += blockDim.x) lcnt[i] = 1;   // slot 0 = self
    __syncthreads();
    int m = binCnt[b];
    if (m > BINCAP) m = BINCAP;
    const int* be = binEdges + (size_t)b * BINCAP;
    int nbase = b << BINSHIFT;
    for (int e = t; e < m; e += blockDim.x) {
        int v = be[e];
        int s = v & 0x1FFFF;
        int dl = v >> 17;
        int pos = atomicAdd(&lcnt[dl], 1);
        if (pos < ELLW) colELL[(size_t)(nbase + dl) * ELLW + pos] = s;
    }
    __syncthreads();
    for (int i = t; i < BINW; i += blockDim.x) {
        int node = nbase + i;
        if (node < n) {
            int c = lcnt[i];
            if (c > ELLW) c = ELLW;
            colELL[(size_t)node * ELLW + 0] = node;        // self edge
            int cpad = (c + 3) & ~3;
            for (int j = c; j < cpad; ++j)
                colELL[(size_t)node * ELLW + j] = n;       // dummy (h'[n] = 0)
            cnt[node] = c;                                  // deg+1
            dinv[node] = rsqrtf((float)c);
        }
    }
}

// One-time f32 -> f16 conversion of the three 64x64 weight matrices.
__global__ void prep_kernel(const float* __restrict__ W1, const float* __restrict__ W2,
                            const float* __restrict__ W3, unsigned short* __restrict__ w1h,
                            unsigned short* __restrict__ w2h, unsigned short* __restrict__ w3h) {
    int t = blockIdx.x * blockDim.x + threadIdx.x;
    if (t < NF * NF) {
        w1h[t] = f2h_u(W1[t]);
        w2h[t] = f2h_u(W2[t]);
        w3h[t] = f2h_u(W3[t]);
    }
}

// ---- layer-1 MFMA GEMM: bufA = dinv * (x @ W1), f16 out via LDS repack ----
__device__ inline void load_W_frags(const unsigned short* __restrict__ Wh, int r16, int kq,
                                    f16x8 bfr[4][2]) {
#pragma unroll
    for (int nt = 0; nt < 4; ++nt)
#pragma unroll
        for (int kh = 0; kh < 2; ++kh) {
            f16x8 f;
#pragma unroll
            for (int j = 0; j < 8; ++j)
                f[j] = __builtin_bit_cast(_Float16,
                        Wh[(kh * 32 + kq * 8 + j) * NF + nt * 16 + r16]);
            bfr[nt][kh] = f;
        }
}

__global__ void __launch_bounds__(256) gemm1_mfma_kernel(const float* __restrict__ A,
                                                         const unsigned short* __restrict__ Wh,
                                                         const float* __restrict__ dinv,
                                                         unsigned short* __restrict__ outB, int n) {
    __shared__ unsigned short T[4][16 * LPITCH];
    int lane = threadIdx.x & 63;
    int r16 = lane & 15, kq = lane >> 4;
    int wv = threadIdx.x >> 6;
    int wid = blockIdx.x * 4 + wv;
    int nw = gridDim.x * 4;
    f16x8 bfr[4][2];
    load_W_frags(Wh, r16, kq, bfr);
    int ntiles = n >> 4;
    for (int t = wid; t < ntiles; t += nw) {
        int r0 = t << 4;
        const float* ar = A + (size_t)(r0 + r16) * NF + kq * 8;
        f16x8 a0, a1;
        float4 v0 = *(const float4*)(ar);
        float4 v1 = *(const float4*)(ar + 4);
        float4 v2 = *(const float4*)(ar + 32);
        float4 v3 = *(const float4*)(ar + 36);
        a0[0] = (_Float16)v0.x; a0[1] = (_Float16)v0.y;
        a0[2] = (_Float16)v0.z; a0[3] = (_Float16)v0.w;
        a0[4] = (_Float16)v1.x; a0[5] = (_Float16)v1.y;
        a0[6] = (_Float16)v1.z; a0[7] = (_Float16)v1.w;
        a1[0] = (_Float16)v2.x; a1[1] = (_Float16)v2.y;
        a1[2] = (_Float16)v2.z; a1[3] = (_Float16)v2.w;
        a1[4] = (_Float16)v3.x; a1[5] = (_Float16)v3.y;
        a1[6] = (_Float16)v3.z; a1[7] = (_Float16)v3.w;
        f32x4 acc[4];
#pragma unroll
        for (int nt = 0; nt < 4; ++nt) {
            acc[nt] = (f32x4)(0.0f);
            acc[nt] = __builtin_amdgcn_mfma_f32_16x16x32_f16(a0, bfr[nt][0], acc[nt], 0, 0, 0);
            acc[nt] = __builtin_amdgcn_mfma_f32_16x16x32_f16(a1, bfr[nt][1], acc[nt], 0, 0, 0);
        }
        float ds[4];
#pragma unroll
        for (int reg = 0; reg < 4; ++reg) ds[reg] = dinv[r0 + kq * 4 + reg];
        unsigned short* Tw = T[wv];
#pragma unroll
        for (int nt = 0; nt < 4; ++nt)
#pragma unroll
            for (int reg = 0; reg < 4; ++reg)
                Tw[(kq * 4 + reg) * LPITCH + nt * 16 + r16] = f2h_u(acc[nt][reg] * ds[reg]);
#pragma unroll
        for (int it = 0; it < 4; ++it) {
            int row = it * 4 + kq;
            uint2 v = *(const uint2*)&Tw[row * LPITCH + r16 * 4];
            *(uint2*)(outB + (size_t)(r0 + row) * NF + r16 * 4) = v;
        }
    }
}

// ---- fused: h = relu(dinv[d]*sum h'[s] + bias); out = dinv * (h @ W) ----
// EXACT r17 structure (best measured). Block = 16 rows; first 32 ELL cols in
// LDS; per-row unrolled quad chunks; depth-2 f16 trees into f32.
__global__ void __launch_bounds__(256) fused_agg_gemm_kernel(
        const unsigned short* __restrict__ hB, const int* __restrict__ colELL,
        const int* __restrict__ cnt, const float* __restrict__ dinv,
        const float* __restrict__ bias, const unsigned short* __restrict__ Wh,
        unsigned short* __restrict__ outB, int n) {
    __shared__ int Icol[16 * 32];                 // 2KB: first 32 cols of 16 rows
    __shared__ int Icnt[16];
    __shared__ unsigned short Tin[2048];          // 16 rows x 64 feats, A-frag order
    __shared__ unsigned short Tout[16 * LPITCH];  // C repack
    int lane = threadIdx.x & 63;
    int wv = threadIdx.x >> 6;
    int es = lane >> 4, fq = lane & 15;
    int r16 = lane & 15, kq = lane >> 4;
    int r0 = blockIdx.x << 4;
    // stage first 32 cols: 512 ints = 128 int4 (8 per row, 128B contiguous runs)
    if (threadIdx.x < 128) {
        int srow = threadIdx.x >> 3, sj = threadIdx.x & 7;
        ((int4*)Icol)[srow * 8 + sj] =
            *(const int4*)(colELL + (size_t)(r0 + srow) * ELLW + sj * 4);
    } else if (threadIdx.x < 144) {
        Icnt[threadIdx.x - 128] = cnt[r0 + threadIdx.x - 128];
    }
    f16x8 bfr0, bfr1;
    {
        f16x8 f0, f1;
#pragma unroll
        for (int j = 0; j < 8; ++j) {
            f0[j] = __builtin_bit_cast(_Float16, Wh[(kq * 8 + j) * NF + wv * 16 + r16]);
            f1[j] = __builtin_bit_cast(_Float16, Wh[(32 + kq * 8 + j) * NF + wv * 16 + r16]);
        }
        bfr0 = f0; bfr1 = f1;
    }
    __syncthreads();
#pragma unroll
    for (int rr = 0; rr < 4; ++rr) {
        int lrow = wv * 4 + rr;
        int row = r0 + lrow;
        int c = Icnt[lrow];
        int nq = (c + 3) >> 2;
        int nqL = nq < 8 ? nq : 8;
        const int* cr = Icol + lrow * 32;
        float a0 = 0.f, a1 = 0.f, a2 = 0.f, a3 = 0.f;
        int q = 0;
        for (; q + 4 <= nqL; q += 4) {
            int s0 = cr[q * 4 + es];
            int s1 = cr[q * 4 + 4 + es];
            int s2 = cr[q * 4 + 8 + es];
            int s3 = cr[q * 4 + 12 + es];
            f16x4 h0 = __builtin_bit_cast(f16x4, *(const uint2*)(hB + (size_t)s0 * NF + fq * 4));
            f16x4 h1 = __builtin_bit_cast(f16x4, *(const uint2*)(hB + (size_t)s1 * NF + fq * 4));
            f16x4 h2 = __builtin_bit_cast(f16x4, *(const uint2*)(hB + (size_t)s2 * NF + fq * 4));
            f16x4 h3 = __builtin_bit_cast(f16x4, *(const uint2*)(hB + (size_t)s3 * NF + fq * 4));
            f16x4 tt = (h0 + h1) + (h2 + h3);     // 6x v_pk_add_f16, depth-2
            a0 += (float)tt[0]; a1 += (float)tt[1];
            a2 += (float)tt[2]; a3 += (float)tt[3];
        }
        for (; q + 2 <= nqL; q += 2) {
            int s0 = cr[q * 4 + es];
            int s1 = cr[q * 4 + 4 + es];
            f16x4 h0 = __builtin_bit_cast(f16x4, *(const uint2*)(hB + (size_t)s0 * NF + fq * 4));
            f16x4 h1 = __builtin_bit_cast(f16x4, *(const uint2*)(hB + (size_t)s1 * NF + fq * 4));
            f16x4 tt = h0 + h1;
            a0 += (float)tt[0]; a1 += (float)tt[1];
            a2 += (float)tt[2]; a3 += (float)tt[3];
        }
        if (q < nqL) {
            int s0 = cr[q * 4 + es];
            f16x4 h0 = __builtin_bit_cast(f16x4, *(const uint2*)(hB + (size_t)s0 * NF + fq * 4));
            a0 += (float)h0[0]; a1 += (float)h0[1];
            a2 += (float)h0[2]; a3 += (float)h0[3];
        }
        if (nq > 8) {   // rare tall row (~1.5e-4): read global tail
            const int* crg = colELL + (size_t)row * ELLW;
            for (int qq = 8; qq < nq; ++qq) {
                int s0 = crg[qq * 4 + es];
                f16x4 h0 = __builtin_bit_cast(f16x4, *(const uint2*)(hB + (size_t)s0 * NF + fq * 4));
                a0 += (float)h0[0]; a1 += (float)h0[1];
                a2 += (float)h0[2]; a3 += (float)h0[3];
            }
        }
        a0 += __shfl_xor(a0, 16); a1 += __shfl_xor(a1, 16);
        a2 += __shfl_xor(a2, 16); a3 += __shfl_xor(a3, 16);
        a0 += __shfl_xor(a0, 32); a1 += __shfl_xor(a1, 32);
        a2 += __shfl_xor(a2, 32); a3 += __shfl_xor(a3, 32);
        if (es == 0) {
            float dd = dinv[row];
            float4 b4 = *(const float4*)(bias + fq * 4);
            a0 = fmaxf(dd * a0 + b4.x, 0.f); a1 = fmaxf(dd * a1 + b4.y, 0.f);
            a2 = fmaxf(dd * a2 + b4.z, 0.f); a3 = fmaxf(dd * a3 + b4.w, 0.f);
            uint2 v;
            v.x = pack_h2(a0, a1);
            v.y = pack_h2(a2, a3);
            int ibase = ((fq >> 3) << 10) + (((fq >> 1) & 3) << 7)
                      + (wv * 4 + rr) * 8 + ((fq & 1) << 2);
            *(uint2*)&Tin[ibase] = v;
        }
    }
    __syncthreads();
    f16x8 A0 = *(const f16x8*)&Tin[lane * 8];
    f16x8 A1 = *(const f16x8*)&Tin[1024 + lane * 8];
    f32x4 acc = (f32x4)(0.0f);
    acc = __builtin_amdgcn_mfma_f32_16x16x32_f16(A0, bfr0, acc, 0, 0, 0);
    acc = __builtin_amdgcn_mfma_f32_16x16x32_f16(A1, bfr1, acc, 0, 0, 0);
    float ds[4];
#pragma unroll
    for (int reg = 0; reg < 4; ++reg) ds[reg] = dinv[r0 + kq * 4 + reg];
#pragma unroll
    for (int reg = 0; reg < 4; ++reg)
        Tout[(kq * 4 + reg) * LPITCH + wv * 16 + r16] = f2h_u(acc[reg] * ds[reg]);
    __syncthreads();
    int t = threadIdx.x;
    int orow = t >> 4, ocq = t & 15;
    uint2 v = *(const uint2*)&Tout[orow * LPITCH + ocq * 4];
    *(uint2*)(outB + (size_t)(r0 + orow) * NF + ocq * 4) = v;
}

// ---- layer-3 aggregation fused with mean-pool: ROW-PARALLEL gather ----
// 32 rows/block, 4 waves. Wave = 8 rows (es) x 8 feature-octets (fq); each
// lane accumulates its row's feats [fq*8, fq*8+8) over all edges (dwordx4
// loads, unroll-4 => 32 scattered lines in flight per wave). No shuffle
// reduce. ELL rows are padded to multiple of 4 => quad loop needs no
// remainder for c<=32.
__global__ void __launch_bounds__(256) gather3_pool_kernel(
        const unsigned short* __restrict__ hB, const int* __restrict__ colELL,
        const int* __restrict__ cnt, const float* __restrict__ dinv,
        const float* __restrict__ bias, const int* __restrict__ batch,
        float* __restrict__ pooled, int n) {
    __shared__ int Icol[32 * 32];     // 4KB: first 32 cols of 32 rows
    __shared__ int Icnt[32];
    __shared__ int Ibatch[32];
    __shared__ float PL[2][NF];
    int t = threadIdx.x;
    int lane = t & 63;
    int wv = t >> 6;
    int es = lane >> 3;               // 0..7: row within wave
    int fq = lane & 7;                // 0..7: feature octet
    int r0 = blockIdx.x << 5;         // 32 rows per block (n % 32 == 0)
    {
        int srow = t >> 3, sj = t & 7;    // 256 threads = 32 rows x 8 int4
        ((int4*)Icol)[t] = *(const int4*)(colELL + (size_t)(r0 + srow) * ELLW + sj * 4);
    }
    if (t < 32) { Icnt[t] = cnt[r0 + t]; Ibatch[t] = batch[r0 + t]; }
    if (t >= 128) PL[(t - 128) >> 6][t & 63] = 0.f;
    __syncthreads();
    int lrow = wv * 8 + es;
    int row = r0 + lrow;
    int c = Icnt[lrow];
    int cpad = (c + 3) & ~3;          // >=4 (self edge), padded with dummies
    int cl4 = cpad < 32 ? cpad : 32;
    const int* cr = Icol + lrow * 32;
    float acc[8];
#pragma unroll
    for (int j = 0; j < 8; ++j) acc[j] = 0.f;
    for (int q = 0; q + 4 <= cl4; q += 4) {
        int s0 = cr[q], s1 = cr[q + 1], s2 = cr[q + 2], s3 = cr[q + 3];
        f16x8 h0 = *(const f16x8*)(hB + (size_t)s0 * NF + fq * 8);
        f16x8 h1 = *(const f16x8*)(hB + (size_t)s1 * NF + fq * 8);
        f16x8 h2 = *(const f16x8*)(hB + (size_t)s2 * NF + fq * 8);
        f16x8 h3 = *(const f16x8*)(hB + (size_t)s3 * NF + fq * 8);
        f16x8 tt = (h0 + h1) + (h2 + h3);   // depth-2 f16 tree (as r17)
#pragma unroll
        for (int j = 0; j < 8; ++j) acc[j] += (float)tt[j];
    }
    if (c > 32) {                      // rare tall row: global tail, quads
        const int* crg = colELL + (size_t)row * ELLW;
        for (int qq = 32; qq + 4 <= cpad; qq += 4) {
            int s0 = crg[qq], s1 = crg[qq + 1], s2 = crg[qq + 2], s3 = crg[qq + 3];
            f16x8 h0 = *(const f16x8*)(hB + (size_t)s0 * NF + fq * 8);
            f16x8 h1 = *(const f16x8*)(hB + (size_t)s1 * NF + fq * 8);
            f16x8 h2 = *(const f16x8*)(hB + (size_t)s2 * NF + fq * 8);
            f16x8 h3 = *(const f16x8*)(hB + (size_t)s3 * NF + fq * 8);
            f16x8 tt = (h0 + h1) + (h2 + h3);
#pragma unroll
            for (int j = 0; j < 8; ++j) acc[j] += (float)tt[j];
        }
    }
    // epilogue: r = dinv*acc + bias (no relu), pool into LDS slots
    float dd = dinv[row];
    float4 bA = *(const float4*)(bias + fq * 8);
    float4 bB = *(const float4*)(bias + fq * 8 + 4);
    float r[8];
    r[0] = dd * acc[0] + bA.x; r[1] = dd * acc[1] + bA.y;
    r[2] = dd * acc[2] + bA.z; r[3] = dd * acc[3] + bA.w;
    r[4] = dd * acc[4] + bB.x; r[5] = dd * acc[5] + bB.y;
    r[6] = dd * acc[6] + bB.z; r[7] = dd * acc[7] + bB.w;
    int g = Ibatch[lrow];
    int gb = Ibatch[0];
    int sel = g - gb;
    if (sel < 2) {
#pragma unroll
        for (int j = 0; j < 8; ++j) atomicAdd(&PL[sel][fq * 8 + j], r[j]);
    } else {                           // window spans >2 graphs (improbable)
#pragma unroll
        for (int j = 0; j < 8; ++j) atomicAdd(&pooled[g * NF + fq * 8 + j], r[j]);
    }
    __syncthreads();
    if (t < 128) {
        int s = t >> 6, f = t & 63;
        float v = PL[s][f];
        if (v != 0.f) atomicAdd(&pooled[(gb + s) * NF + f], v);
    }
}

// counts[g] = #nodes in graph g (LDS histogram of batch)
__global__ void counts_kernel(const int* __restrict__ batch, float* __restrict__ counts, int n) {
    __shared__ int h[64];
    int t = threadIdx.x;
    if (t < 64) h[t] = 0;
    __syncthreads();
    for (int i = blockIdx.x * blockDim.x + t; i < n; i += gridDim.x * blockDim.x)
        atomicAdd(&h[batch[i]], 1);
    __syncthreads();
    if (t < 64 && h[t] > 0) atomicAdd(&counts[t], (float)h[t]);
}

// out[g][c] = (pooled[g][:]/max(cnt,1)) @ Wl[:,c] + bl[c]
__global__ void final_kernel(const float* __restrict__ pooled, const float* __restrict__ counts,
                             const float* __restrict__ Wl, const float* __restrict__ bl,
                             float* __restrict__ out) {
    int t = threadIdx.x;  // 128 threads: g = t>>1, c = t&1
    int g = t >> 1, c = t & 1;
    float inv = 1.0f / fmaxf(counts[g], 1.0f);
    float s = 0.0f;
#pragma unroll
    for (int j = 0; j < NF; ++j) s += pooled[g * NF + j] * Wl[j * 2 + c];
    out[t] = s * inv + bl[c];
}

extern "C" void kernel_launch(void* const* d_in, const int* in_sizes, int n_in,
                              void* d_out, int out_size, void* d_ws, size_t ws_size,
                              hipStream_t stream) {
    const float* x     = (const float*)d_in[0];
    const int*   ei    = (const int*)d_in[1];
    const int*   batch = (const int*)d_in[2];
    const float* W1    = (const float*)d_in[3];
    const float* b1    = (const float*)d_in[4];
    const float* W2    = (const float*)d_in[5];
    const float* b2    = (const float*)d_in[6];
    const float* W3    = (const float*)d_in[7];
    const float* b3    = (const float*)d_in[8];
    const float* Wl    = (const float*)d_in[9];
    const float* bl    = (const float*)d_in[10];
    float* out = (float*)d_out;

    const int n  = in_sizes[0] / NF;   // 100000 (divisible by 32)
    const int nE = in_sizes[1] / 2;    // 1600000
    const int* src = ei;
    const int* dst = ei + nE;

    // workspace layout (256B-aligned)
    char* ws = (char*)d_ws;
    auto alloc = [&](size_t bytes) {
        char* p = ws;
        ws += (bytes + 255) & ~(size_t)255;
        return p;
    };
    unsigned short* bufA = (unsigned short*)alloc((size_t)(n + 16) * NF * 2); // +dummy row
    unsigned short* bufB = (unsigned short*)alloc((size_t)(n + 16) * NF * 2);
    float* scratch = (float*)alloc((size_t)n * NF * 4);                  // binEdges alias
    int*   binEdges = (int*)scratch;                                     // build phase only (7.2 MB)
    int*   colELL = (int*)alloc((size_t)n * ELLW * 4);                   // 25.7 MB
    float* dinv   = (float*)alloc((size_t)(n + 16) * 4);                 // +dummy
    int*   cnt    = (int*)alloc((size_t)n * 4);
    unsigned short* w1h = (unsigned short*)alloc((size_t)NF * NF * 2);
    unsigned short* w2h = (unsigned short*)alloc((size_t)NF * NF * 2);
    unsigned short* w3h = (unsigned short*)alloc((size_t)NF * NF * 2);
    // zero-init tail: binCnt | pooled | counts (one memset)
    char*  ztail  = ws;
    int*   binCnt = (int*)alloc(NB * 4);
    float* pooled = (float*)alloc(64 * NF * 4);
    float* counts = (float*)alloc(64 * 4);
    size_t zbytes = (size_t)(ws - ztail);

    (void)hipMemsetAsync(ztail, 0, zbytes, stream);

    // ---- binned ELL build (once, reused by all 3 layers) ----
    const int chunk = 3200;
    binA_kernel<<<(nE + chunk - 1) / chunk, 256, 0, stream>>>(src, dst, binCnt, binEdges, nE, chunk);
    binB_kernel<<<NB, 512, 0, stream>>>(binEdges, binCnt, cnt, dinv, colELL, n,
                                        (unsigned int*)(bufA + (size_t)n * NF),
                                        (unsigned int*)(bufB + (size_t)n * NF));
    counts_kernel<<<98, 1024, 0, stream>>>(batch, counts, n);
    prep_kernel<<<16, 256, 0, stream>>>(W1, W2, W3, w1h, w2h, w3h);

    const int tile_grid = n >> 4;     // 6250 blocks of 16 rows

    // conv1 GEMM: bufA = dinv * (x @ W1)
    gemm1_mfma_kernel<<<1563, 256, 0, stream>>>(x, w1h, dinv, bufA, n);
    // fused conv1-agg + conv2 GEMM: bufB = dinv * (relu(AGG'(bufA)+b1) @ W2)
    fused_agg_gemm_kernel<<<tile_grid, 256, 0, stream>>>(bufA, colELL, cnt, dinv, b1, w2h, bufB, n);
    // fused conv2-agg + conv3 GEMM: bufA = dinv * (relu(AGG'(bufB)+b2) @ W3)
    fused_agg_gemm_kernel<<<tile_grid, 256, 0, stream>>>(bufB, colELL, cnt, dinv, b2, w3h, bufA, n);
    // conv3 aggregation + mean-pool (row-parallel gather, 32 rows/block)
    gather3_pool_kernel<<<n >> 5, 256, 0, stream>>>(bufA, colELL, cnt, dinv, b3,
                                                    batch, pooled, n);

    final_kernel<<<1, 128, 0, stream>>>(pooled, counts, Wl, bl, out);
}

// Round 7
// 252.244 us; speedup vs baseline: 1.2069x; 1.0144x over previous
//
#include <hip/hip_runtime.h>

// GCN: 3x GCNConv(64->64) + global_mean_pool + linear(64->2)
// N=100000 nodes, E=1.6M edges, 64 graphs.
// Round 21: port row-parallel gather (r20's gather3_pool win) to fused_agg.
//   Block = 32 rows = two 16-row MFMA tiles; wave = 8 rows x 8 feature-octets.
//   Each lane accumulates its row's 8 feats (dwordx4 loads, depth-2 f16 tree,
//   f32 across quads) and writes its A-fragment slot directly (r17 Tin read
//   layout). Each wave MFMAs one tile x two 16-col slabs. No shuffle reduce,
//   no divergent epilogue. gather3_pool/binA/binB/gemm1 = r20 (controls).

#define NF 64
#define ELLW 64
#define BINSHIFT 9
#define BINW 512
#define NB 196         // ceil(100000 / 512)
#define BINCAP 9216    // per-bin edge cap: mean 8163 + ~11 sigma
#define LPITCH 68      // ushort pitch for C-repack LDS tile

typedef __attribute__((ext_vector_type(8))) _Float16 f16x8;  // 8 f16 (4 VGPRs)
typedef __attribute__((ext_vector_type(4))) _Float16 f16x4;  // 4 f16 (2 VGPRs)
typedef __attribute__((ext_vector_type(4))) float f32x4;     // 4 fp32 acc

__device__ inline unsigned short f2h_u(float f) {
    return __builtin_bit_cast(unsigned short, (_Float16)f);   // v_cvt_f16_f32 (RNE)
}
__device__ inline unsigned int pack_h2(float a, float b) {
    unsigned int ua = f2h_u(a), ub = f2h_u(b);
    return ua | (ub << 16);
}

// Phase A: partition edges by dst bin (LDS histogram, contiguous appends).
__global__ void binA_kernel(const int* __restrict__ src, const int* __restrict__ dst,
                            int* __restrict__ binCnt, int* __restrict__ binEdges,
                            int nE, int chunk) {
    __shared__ int hist[NB];
    __shared__ int base[NB];
    int t = threadIdx.x;
    if (t < NB) hist[t] = 0;
    __syncthreads();
    int e0 = blockIdx.x * chunk;
    int e1 = min(e0 + chunk, nE);
    for (int e = e0 + t; e < e1; e += blockDim.x) {
        int b = dst[e] >> BINSHIFT;
        atomicAdd(&hist[b], 1);
    }
    __syncthreads();
    if (t < NB) {
        base[t] = atomicAdd(&binCnt[t], hist[t]);
        hist[t] = 0;
    }
    __syncthreads();
    for (int e = e0 + t; e < e1; e += blockDim.x) {
        int d = dst[e];
        int b = d >> BINSHIFT;
        int pos = base[b] + atomicAdd(&hist[b], 1);
        if (pos < BINCAP)
            binEdges[(size_t)b * BINCAP + pos] = src[e] | ((d & (BINW - 1)) << 17);
    }
}

// Phase B: one block per bin; ELL slot 0 = self edge; rows padded to multiple
// of 4 with dummy index n (h'[n] = 0). Block 0 zeroes dummy feature rows.
__global__ void __launch_bounds__(512) binB_kernel(const int* __restrict__ binEdges,
                            const int* __restrict__ binCnt, int* __restrict__ cnt,
                            float* __restrict__ dinv, int* __restrict__ colELL, int n,
                            unsigned int* __restrict__ dummyA, unsigned int* __restrict__ dummyB) {
    __shared__ int lcnt[BINW];
    int t = threadIdx.x;
    int b = blockIdx.x;
    if (b == 0 && t < 32) { dummyA[t] = 0u; dummyB[t] = 0u; }   // h'[n] = 0 (128B each)
    for (int i = t; i < BINW; i += blockDim.x) lcnt[i] = 1;   // slot 0 = self
    __syncthreads();
    int m = binCnt[b];
    if (m > BINCAP) m = BINCAP;
    const int* be = binEdges + (size_t)b * BINCAP;
    int nbase = b << BINSHIFT;
    for (int e = t; e < m; e += blockDim.x) {
        int v = be[e];
        int s = v & 0x1FFFF;
        int dl = v >> 17;
        int pos = atomicAdd(&lcnt[dl], 1);
        if (pos < ELLW) colELL[(size_t)(nbase + dl) * ELLW + pos] = s;
    }
    __syncthreads();
    for (int i = t; i < BINW; i += blockDim.x) {
        int node = nbase + i;
        if (node < n) {
            int c = lcnt[i];
            if (c > ELLW) c = ELLW;
            colELL[(size_t)node * ELLW + 0] = node;        // self edge
            int cpad = (c + 3) & ~3;
            for (int j = c; j < cpad; ++j)
                colELL[(size_t)node * ELLW + j] = n;       // dummy (h'[n] = 0)
            cnt[node] = c;                                  // deg+1
            dinv[node] = rsqrtf((float)c);
        }
    }
}

// One-time f32 -> f16 conversion of the three 64x64 weight matrices.
__global__ void prep_kernel(const float* __restrict__ W1, const float* __restrict__ W2,
                            const float* __restrict__ W3, unsigned short* __restrict__ w1h,
                            unsigned short* __restrict__ w2h, unsigned short* __restrict__ w3h) {
    int t = blockIdx.x * blockDim.x + threadIdx.x;
    if (t < NF * NF) {
        w1h[t] = f2h_u(W1[t]);
        w2h[t] = f2h_u(W2[t]);
        w3h[t] = f2h_u(W3[t]);
    }
}

// ---- layer-1 MFMA GEMM: bufA = dinv * (x @ W1), f16 out via LDS repack ----
__device__ inline void load_W_frags(const unsigned short* __restrict__ Wh, int r16, int kq,
                                    f16x8 bfr[4][2]) {
#pragma unroll
    for (int nt = 0; nt < 4; ++nt)
#pragma unroll
        for (int kh = 0; kh < 2; ++kh) {
            f16x8 f;
#pragma unroll
            for (int j = 0; j < 8; ++j)
                f[j] = __builtin_bit_cast(_Float16,
                        Wh[(kh * 32 + kq * 8 + j) * NF + nt * 16 + r16]);
            bfr[nt][kh] = f;
        }
}

__global__ void __launch_bounds__(256) gemm1_mfma_kernel(const float* __restrict__ A,
                                                         const unsigned short* __restrict__ Wh,
                                                         const float* __restrict__ dinv,
                                                         unsigned short* __restrict__ outB, int n) {
    __shared__ unsigned short T[4][16 * LPITCH];
    int lane = threadIdx.x & 63;
    int r16 = lane & 15, kq = lane >> 4;
    int wv = threadIdx.x >> 6;
    int wid = blockIdx.x * 4 + wv;
    int nw = gridDim.x * 4;
    f16x8 bfr[4][2];
    load_W_frags(Wh, r16, kq, bfr);
    int ntiles = n >> 4;
    for (int t = wid; t < ntiles; t += nw) {
        int r0 = t << 4;
        const float* ar = A + (size_t)(r0 + r16) * NF + kq * 8;
        f16x8 a0, a1;
        float4 v0 = *(const float4*)(ar);
        float4 v1 = *(const float4*)(ar + 4);
        float4 v2 = *(const float4*)(ar + 32);
        float4 v3 = *(const float4*)(ar + 36);
        a0[0] = (_Float16)v0.x; a0[1] = (_Float16)v0.y;
        a0[2] = (_Float16)v0.z; a0[3] = (_Float16)v0.w;
        a0[4] = (_Float16)v1.x; a0[5] = (_Float16)v1.y;
        a0[6] = (_Float16)v1.z; a0[7] = (_Float16)v1.w;
        a1[0] = (_Float16)v2.x; a1[1] = (_Float16)v2.y;
        a1[2] = (_Float16)v2.z; a1[3] = (_Float16)v2.w;
        a1[4] = (_Float16)v3.x; a1[5] = (_Float16)v3.y;
        a1[6] = (_Float16)v3.z; a1[7] = (_Float16)v3.w;
        f32x4 acc[4];
#pragma unroll
        for (int nt = 0; nt < 4; ++nt) {
            acc[nt] = (f32x4)(0.0f);
            acc[nt] = __builtin_amdgcn_mfma_f32_16x16x32_f16(a0, bfr[nt][0], acc[nt], 0, 0, 0);
            acc[nt] = __builtin_amdgcn_mfma_f32_16x16x32_f16(a1, bfr[nt][1], acc[nt], 0, 0, 0);
        }
        float ds[4];
#pragma unroll
        for (int reg = 0; reg < 4; ++reg) ds[reg] = dinv[r0 + kq * 4 + reg];
        unsigned short* Tw = T[wv];
#pragma unroll
        for (int nt = 0; nt < 4; ++nt)
#pragma unroll
            for (int reg = 0; reg < 4; ++reg)
                Tw[(kq * 4 + reg) * LPITCH + nt * 16 + r16] = f2h_u(acc[nt][reg] * ds[reg]);
#pragma unroll
        for (int it = 0; it < 4; ++it) {
            int row = it * 4 + kq;
            uint2 v = *(const uint2*)&Tw[row * LPITCH + r16 * 4];
            *(uint2*)(outB + (size_t)(r0 + row) * NF + r16 * 4) = v;
        }
    }
}

// ---- fused: h = relu(dinv[d]*sum h'[s] + bias); out = dinv * (h @ W) ----
// Row-parallel gather (r20 shape): block = 32 rows = 2 MFMA tiles; wave = 8
// rows x 8 feature-octets; lane owns row lrow feats [fq*8, fq*8+8). A-frag
// written directly to Tin (r17 linear layout, conflict-free reads). Each wave
// MFMAs tile (wv>>1), col slabs 2*(wv&1), 2*(wv&1)+1.
__global__ void __launch_bounds__(256) fused_agg_gemm_kernel(
        const unsigned short* __restrict__ hB, const int* __restrict__ colELL,
        const int* __restrict__ cnt, const float* __restrict__ dinv,
        const float* __restrict__ bias, const unsigned short* __restrict__ Wh,
        unsigned short* __restrict__ outB, int n) {
    __shared__ int Icol[32 * 32];                    // 4KB: first 32 cols of 32 rows
    __shared__ int Icnt[32];
    __shared__ unsigned short Tin[2][2048];          // per tile: 16 rows x 64 feats, A-frag order
    __shared__ unsigned short Tout[2][16 * LPITCH];  // per tile C repack
    int t = threadIdx.x;
    int lane = t & 63;
    int wv = t >> 6;
    int es = lane >> 3;               // 0..7: row within wave's 8-row strip
    int fq = lane & 7;                // 0..7: feature octet
    int r16 = lane & 15, kq = lane >> 4;
    int r0 = (int)(blockIdx.x << 5);  // 32 rows per block
    {
        int srow = t >> 3, sj = t & 7;    // 256 threads = 32 rows x 8 int4
        ((int4*)Icol)[t] = *(const int4*)(colELL + (size_t)(r0 + srow) * ELLW + sj * 4);
    }
    if (t < 32) Icnt[t] = cnt[r0 + t];
    // W frags: wave wv covers col slabs s0 = 2*(wv&1), s0+1 (16 cols each)
    int s0 = (wv & 1) << 1;
    f16x8 bfr[2][2];
#pragma unroll
    for (int si = 0; si < 2; ++si)
#pragma unroll
        for (int kh = 0; kh < 2; ++kh) {
            f16x8 f;
#pragma unroll
            for (int j = 0; j < 8; ++j)
                f[j] = __builtin_bit_cast(_Float16,
                        Wh[(kh * 32 + kq * 8 + j) * NF + (s0 + si) * 16 + r16]);
            bfr[si][kh] = f;
        }
    __syncthreads();
    // ---- row-parallel gather (identical shape to gather3_pool) ----
    int lrow = wv * 8 + es;
    int row = r0 + lrow;
    int c = Icnt[lrow];
    int cpad = (c + 3) & ~3;
    int cl4 = cpad < 32 ? cpad : 32;
    const int* cr = Icol + lrow * 32;
    float acc[8];
#pragma unroll
    for (int j = 0; j < 8; ++j) acc[j] = 0.f;
    for (int q = 0; q + 4 <= cl4; q += 4) {
        int s0e = cr[q], s1e = cr[q + 1], s2e = cr[q + 2], s3e = cr[q + 3];
        f16x8 h0 = *(const f16x8*)(hB + (size_t)s0e * NF + fq * 8);
        f16x8 h1 = *(const f16x8*)(hB + (size_t)s1e * NF + fq * 8);
        f16x8 h2 = *(const f16x8*)(hB + (size_t)s2e * NF + fq * 8);
        f16x8 h3 = *(const f16x8*)(hB + (size_t)s3e * NF + fq * 8);
        f16x8 tt = (h0 + h1) + (h2 + h3);   // depth-2 f16 tree
#pragma unroll
        for (int j = 0; j < 8; ++j) acc[j] += (float)tt[j];
    }
    if (c > 32) {                      // rare tall row: global tail
        const int* crg = colELL + (size_t)row * ELLW;
        for (int qq = 32; qq + 4 <= cpad; qq += 4) {
            int s0e = crg[qq], s1e = crg[qq + 1], s2e = crg[qq + 2], s3e = crg[qq + 3];
            f16x8 h0 = *(const f16x8*)(hB + (size_t)s0e * NF + fq * 8);
            f16x8 h1 = *(const f16x8*)(hB + (size_t)s1e * NF + fq * 8);
            f16x8 h2 = *(const f16x8*)(hB + (size_t)s2e * NF + fq * 8);
            f16x8 h3 = *(const f16x8*)(hB + (size_t)s3e * NF + fq * 8);
            f16x8 tt = (h0 + h1) + (h2 + h3);
#pragma unroll
            for (int j = 0; j < 8; ++j) acc[j] += (float)tt[j];
        }
    }
    // epilogue: h = relu(dinv*acc + bias); write lane's A-frag slot
    {
        float dd = dinv[row];
        float4 bA = *(const float4*)(bias + fq * 8);
        float4 bB = *(const float4*)(bias + fq * 8 + 4);
        float r0f = fmaxf(dd * acc[0] + bA.x, 0.f), r1f = fmaxf(dd * acc[1] + bA.y, 0.f);
        float r2f = fmaxf(dd * acc[2] + bA.z, 0.f), r3f = fmaxf(dd * acc[3] + bA.w, 0.f);
        float r4f = fmaxf(dd * acc[4] + bB.x, 0.f), r5f = fmaxf(dd * acc[5] + bB.y, 0.f);
        float r6f = fmaxf(dd * acc[6] + bB.z, 0.f), r7f = fmaxf(dd * acc[7] + bB.w, 0.f);
        int4 v;
        v.x = (int)pack_h2(r0f, r1f);
        v.y = (int)pack_h2(r2f, r3f);
        v.z = (int)pack_h2(r4f, r5f);
        v.w = (int)pack_h2(r6f, r7f);
        int tile = lrow >> 4;
        int idx = ((fq >> 2) << 10) + (((fq & 3) * 16 + (lrow & 15)) << 3);
        *(int4*)&Tin[tile][idx] = v;
    }
    __syncthreads();
    // ---- MFMA: wave wv -> tile (wv>>1), slabs s0, s0+1 ----
    int tile = wv >> 1;
    f16x8 A0 = *(const f16x8*)&Tin[tile][lane * 8];
    f16x8 A1 = *(const f16x8*)&Tin[tile][1024 + lane * 8];
    float ds[4];
#pragma unroll
    for (int reg = 0; reg < 4; ++reg) ds[reg] = dinv[r0 + tile * 16 + kq * 4 + reg];
#pragma unroll
    for (int si = 0; si < 2; ++si) {
        f32x4 accC = (f32x4)(0.0f);
        accC = __builtin_amdgcn_mfma_f32_16x16x32_f16(A0, bfr[si][0], accC, 0, 0, 0);
        accC = __builtin_amdgcn_mfma_f32_16x16x32_f16(A1, bfr[si][1], accC, 0, 0, 0);
#pragma unroll
        for (int reg = 0; reg < 4; ++reg)
            Tout[tile][(kq * 4 + reg) * LPITCH + (s0 + si) * 16 + r16] =
                f2h_u(accC[reg] * ds[reg]);
    }
    __syncthreads();
    // store 32 rows x 64 feats
    {
        int orow = t >> 3, oc = t & 7;
        const unsigned short* p = &Tout[orow >> 4][(orow & 15) * LPITCH + oc * 8];
        uint2 v0 = *(const uint2*)(p);
        uint2 v1 = *(const uint2*)(p + 4);
        int4 v; v.x = (int)v0.x; v.y = (int)v0.y; v.z = (int)v1.x; v.w = (int)v1.y;
        *(int4*)(outB + (size_t)(r0 + orow) * NF + oc * 8) = v;
    }
}

// ---- layer-3 aggregation fused with mean-pool: ROW-PARALLEL gather (r20) ----
__global__ void __launch_bounds__(256) gather3_pool_kernel(
        const unsigned short* __restrict__ hB, const int* __restrict__ colELL,
        const int* __restrict__ cnt, const float* __restrict__ dinv,
        const float* __restrict__ bias, const int* __restrict__ batch,
        float* __restrict__ pooled, int n) {
    __shared__ int Icol[32 * 32];     // 4KB: first 32 cols of 32 rows
    __shared__ int Icnt[32];
    __shared__ int Ibatch[32];
    __shared__ float PL[2][NF];
    int t = threadIdx.x;
    int lane = t & 63;
    int wv = t >> 6;
    int es = lane >> 3;               // 0..7: row within wave
    int fq = lane & 7;                // 0..7: feature octet
    int r0 = (int)(blockIdx.x << 5);  // 32 rows per block (n % 32 == 0)
    {
        int srow = t >> 3, sj = t & 7;    // 256 threads = 32 rows x 8 int4
        ((int4*)Icol)[t] = *(const int4*)(colELL + (size_t)(r0 + srow) * ELLW + sj * 4);
    }
    if (t < 32) { Icnt[t] = cnt[r0 + t]; Ibatch[t] = batch[r0 + t]; }
    if (t >= 128) PL[(t - 128) >> 6][t & 63] = 0.f;
    __syncthreads();
    int lrow = wv * 8 + es;
    int row = r0 + lrow;
    int c = Icnt[lrow];
    int cpad = (c + 3) & ~3;          // >=4 (self edge), padded with dummies
    int cl4 = cpad < 32 ? cpad : 32;
    const int* cr = Icol + lrow * 32;
    float acc[8];
#pragma unroll
    for (int j = 0; j < 8; ++j) acc[j] = 0.f;
    for (int q = 0; q + 4 <= cl4; q += 4) {
        int s0 = cr[q], s1 = cr[q + 1], s2 = cr[q + 2], s3 = cr[q + 3];
        f16x8 h0 = *(const f16x8*)(hB + (size_t)s0 * NF + fq * 8);
        f16x8 h1 = *(const f16x8*)(hB + (size_t)s1 * NF + fq * 8);
        f16x8 h2 = *(const f16x8*)(hB + (size_t)s2 * NF + fq * 8);
        f16x8 h3 = *(const f16x8*)(hB + (size_t)s3 * NF + fq * 8);
        f16x8 tt = (h0 + h1) + (h2 + h3);   // depth-2 f16 tree (as r17)
#pragma unroll
        for (int j = 0; j < 8; ++j) acc[j] += (float)tt[j];
    }
    if (c > 32) {                      // rare tall row: global tail, quads
        const int* crg = colELL + (size_t)row * ELLW;
        for (int qq = 32; qq + 4 <= cpad; qq += 4) {
            int s0 = crg[qq], s1 = crg[qq + 1], s2 = crg[qq + 2], s3 = crg[qq + 3];
            f16x8 h0 = *(const f16x8*)(hB + (size_t)s0 * NF + fq * 8);
            f16x8 h1 = *(const f16x8*)(hB + (size_t)s1 * NF + fq * 8);
            f16x8 h2 = *(const f16x8*)(hB + (size_t)s2 * NF + fq * 8);
            f16x8 h3 = *(const f16x8*)(hB + (size_t)s3 * NF + fq * 8);
            f16x8 tt = (h0 + h1) + (h2 + h3);
#pragma unroll
            for (int j = 0; j < 8; ++j) acc[j] += (float)tt[j];
        }
    }
    // epilogue: r = dinv*acc + bias (no relu), pool into LDS slots
    float dd = dinv[row];
    float4 bA = *(const float4*)(bias + fq * 8);
    float4 bB = *(const float4*)(bias + fq * 8 + 4);
    float r[8];
    r[0] = dd * acc[0] + bA.x; r[1] = dd * acc[1] + bA.y;
    r[2] = dd * acc[2] + bA.z; r[3] = dd * acc[3] + bA.w;
    r[4] = dd * acc[4] + bB.x; r[5] = dd * acc[5] + bB.y;
    r[6] = dd * acc[6] + bB.z; r[7] = dd * acc[7] + bB.w;
    int g = Ibatch[lrow];
    int gb = Ibatch[0];
    int sel = g - gb;
    if (sel < 2) {
#pragma unroll
        for (int j = 0; j < 8; ++j) atomicAdd(&PL[sel][fq * 8 + j], r[j]);
    } else {                           // window spans >2 graphs (improbable)
#pragma unroll
        for (int j = 0; j < 8; ++j) atomicAdd(&pooled[g * NF + fq * 8 + j], r[j]);
    }
    __syncthreads();
    if (t < 128) {
        int s = t >> 6, f = t & 63;
        float v = PL[s][f];
        if (v != 0.f) atomicAdd(&pooled[(gb + s) * NF + f], v);
    }
}

// counts[g] = #nodes in graph g (LDS histogram of batch)
__global__ void counts_kernel(const int* __restrict__ batch, float* __restrict__ counts, int n) {
    __shared__ int h[64];
    int t = threadIdx.x;
    if (t < 64) h[t] = 0;
    __syncthreads();
    for (int i = blockIdx.x * blockDim.x + t; i < n; i += gridDim.x * blockDim.x)
        atomicAdd(&h[batch[i]], 1);
    __syncthreads();
    if (t < 64 && h[t] > 0) atomicAdd(&counts[t], (float)h[t]);
}

// out[g][c] = (pooled[g][:]/max(cnt,1)) @ Wl[:,c] + bl[c]
__global__ void final_kernel(const float* __restrict__ pooled, const float* __restrict__ counts,
                             const float* __restrict__ Wl, const float* __restrict__ bl,
                             float* __restrict__ out) {
    int t = threadIdx.x;  // 128 threads: g = t>>1, c = t&1
    int g = t >> 1, c = t & 1;
    float inv = 1.0f / fmaxf(counts[g], 1.0f);
    float s = 0.0f;
#pragma unroll
    for (int j = 0; j < NF; ++j) s += pooled[g * NF + j] * Wl[j * 2 + c];
    out[t] = s * inv + bl[c];
}

extern "C" void kernel_launch(void* const* d_in, const int* in_sizes, int n_in,
                              void* d_out, int out_size, void* d_ws, size_t ws_size,
                              hipStream_t stream) {
    const float* x     = (const float*)d_in[0];
    const int*   ei    = (const int*)d_in[1];
    const int*   batch = (const int*)d_in[2];
    const float* W1    = (const float*)d_in[3];
    const float* b1    = (const float*)d_in[4];
    const float* W2    = (const float*)d_in[5];
    const float* b2    = (const float*)d_in[6];
    const float* W3    = (const float*)d_in[7];
    const float* b3    = (const float*)d_in[8];
    const float* Wl    = (const float*)d_in[9];
    const float* bl    = (const float*)d_in[10];
    float* out = (float*)d_out;

    const int n  = in_sizes[0] / NF;   // 100000 (divisible by 32)
    const int nE = in_sizes[1] / 2;    // 1600000
    const int* src = ei;
    const int* dst = ei + nE;

    // workspace layout (256B-aligned)
    char* ws = (char*)d_ws;
    auto alloc = [&](size_t bytes) {
        char* p = ws;
        ws += (bytes + 255) & ~(size_t)255;
        return p;
    };
    unsigned short* bufA = (unsigned short*)alloc((size_t)(n + 16) * NF * 2); // +dummy row
    unsigned short* bufB = (unsigned short*)alloc((size_t)(n + 16) * NF * 2);
    float* scratch = (float*)alloc((size_t)n * NF * 4);                  // binEdges alias
    int*   binEdges = (int*)scratch;                                     // build phase only (7.2 MB)
    int*   colELL = (int*)alloc((size_t)n * ELLW * 4);                   // 25.7 MB
    float* dinv   = (float*)alloc((size_t)(n + 16) * 4);                 // +dummy
    int*   cnt    = (int*)alloc((size_t)n * 4);
    unsigned short* w1h = (unsigned short*)alloc((size_t)NF * NF * 2);
    unsigned short* w2h = (unsigned short*)alloc((size_t)NF * NF * 2);
    unsigned short* w3h = (unsigned short*)alloc((size_t)NF * NF * 2);
    // zero-init tail: binCnt | pooled | counts (one memset)
    char*  ztail  = ws;
    int*   binCnt = (int*)alloc(NB * 4);
    float* pooled = (float*)alloc(64 * NF * 4);
    float* counts = (float*)alloc(64 * 4);
    size_t zbytes = (size_t)(ws - ztail);

    (void)hipMemsetAsync(ztail, 0, zbytes, stream);

    // ---- binned ELL build (once, reused by all 3 layers) ----
    const int chunk = 3200;
    binA_kernel<<<(nE + chunk - 1) / chunk, 256, 0, stream>>>(src, dst, binCnt, binEdges, nE, chunk);
    binB_kernel<<<NB, 512, 0, stream>>>(binEdges, binCnt, cnt, dinv, colELL, n,
                                        (unsigned int*)(bufA + (size_t)n * NF),
                                        (unsigned int*)(bufB + (size_t)n * NF));
    counts_kernel<<<98, 1024, 0, stream>>>(batch, counts, n);
    prep_kernel<<<16, 256, 0, stream>>>(W1, W2, W3, w1h, w2h, w3h);

    // conv1 GEMM: bufA = dinv * (x @ W1)
    gemm1_mfma_kernel<<<1563, 256, 0, stream>>>(x, w1h, dinv, bufA, n);
    // fused conv1-agg + conv2 GEMM: bufB = dinv * (relu(AGG'(bufA)+b1) @ W2)
    fused_agg_gemm_kernel<<<n >> 5, 256, 0, stream>>>(bufA, colELL, cnt, dinv, b1, w2h, bufB, n);
    // fused conv2-agg + conv3 GEMM: bufA = dinv * (relu(AGG'(bufB)+b2) @ W3)
    fused_agg_gemm_kernel<<<n >> 5, 256, 0, stream>>>(bufB, colELL, cnt, dinv, b2, w3h, bufA, n);
    // conv3 aggregation + mean-pool (row-parallel gather, 32 rows/block)
    gather3_pool_kernel<<<n >> 5, 256, 0, stream>>>(bufA, colELL, cnt, dinv, b3,
                                                    batch, pooled, n);

    final_kernel<<<1, 128, 0, stream>>>(pooled, counts, Wl, bl, out);
}

// Round 8
// 249.242 us; speedup vs baseline: 1.2215x; 1.0120x over previous
//
#include <hip/hip_runtime.h>

// GCN: 3x GCNConv(64->64) + global_mean_pool + linear(64->2)
// N=100000 nodes, E=1.6M edges, 64 graphs.
// Round 22: deepen gather MLP 4 -> 8. The row-parallel gather (r20/r21) now
// issues TWO quads (8 independent dwordx4 loads) per iteration before any
// dependent f16-tree add; remainder is one quad. Same depth-2 trees + f32
// accumulation per quad (numerics unchanged). Applied to fused_agg (x2) and
// gather3_pool. Everything else = r21.

#define NF 64
#define ELLW 64
#define BINSHIFT 9
#define BINW 512
#define NB 196         // ceil(100000 / 512)
#define BINCAP 9216    // per-bin edge cap: mean 8163 + ~11 sigma
#define LPITCH 68      // ushort pitch for C-repack LDS tile

typedef __attribute__((ext_vector_type(8))) _Float16 f16x8;  // 8 f16 (4 VGPRs)
typedef __attribute__((ext_vector_type(4))) _Float16 f16x4;  // 4 f16 (2 VGPRs)
typedef __attribute__((ext_vector_type(4))) float f32x4;     // 4 fp32 acc

__device__ inline unsigned short f2h_u(float f) {
    return __builtin_bit_cast(unsigned short, (_Float16)f);   // v_cvt_f16_f32 (RNE)
}
__device__ inline unsigned int pack_h2(float a, float b) {
    unsigned int ua = f2h_u(a), ub = f2h_u(b);
    return ua | (ub << 16);
}

// Phase A: partition edges by dst bin (LDS histogram, contiguous appends).
__global__ void binA_kernel(const int* __restrict__ src, const int* __restrict__ dst,
                            int* __restrict__ binCnt, int* __restrict__ binEdges,
                            int nE, int chunk) {
    __shared__ int hist[NB];
    __shared__ int base[NB];
    int t = threadIdx.x;
    if (t < NB) hist[t] = 0;
    __syncthreads();
    int e0 = blockIdx.x * chunk;
    int e1 = min(e0 + chunk, nE);
    for (int e = e0 + t; e < e1; e += blockDim.x) {
        int b = dst[e] >> BINSHIFT;
        atomicAdd(&hist[b], 1);
    }
    __syncthreads();
    if (t < NB) {
        base[t] = atomicAdd(&binCnt[t], hist[t]);
        hist[t] = 0;
    }
    __syncthreads();
    for (int e = e0 + t; e < e1; e += blockDim.x) {
        int d = dst[e];
        int b = d >> BINSHIFT;
        int pos = base[b] + atomicAdd(&hist[b], 1);
        if (pos < BINCAP)
            binEdges[(size_t)b * BINCAP + pos] = src[e] | ((d & (BINW - 1)) << 17);
    }
}

// Phase B: one block per bin; ELL slot 0 = self edge; rows padded to multiple
// of 4 with dummy index n (h'[n] = 0). Block 0 zeroes dummy feature rows.
__global__ void __launch_bounds__(512) binB_kernel(const int* __restrict__ binEdges,
                            const int* __restrict__ binCnt, int* __restrict__ cnt,
                            float* __restrict__ dinv, int* __restrict__ colELL, int n,
                            unsigned int* __restrict__ dummyA, unsigned int* __restrict__ dummyB) {
    __shared__ int lcnt[BINW];
    int t = threadIdx.x;
    int b = blockIdx.x;
    if (b == 0 && t < 32) { dummyA[t] = 0u; dummyB[t] = 0u; }   // h'[n] = 0 (128B each)
    for (int i = t; i < BINW; i += blockDim.x) lcnt[i] = 1;   // slot 0 = self
    __syncthreads();
    int m = binCnt[b];
    if (m > BINCAP) m = BINCAP;
    const int* be = binEdges + (size_t)b * BINCAP;
    int nbase = b << BINSHIFT;
    for (int e = t; e < m; e += blockDim.x) {
        int v = be[e];
        int s = v & 0x1FFFF;
        int dl = v >> 17;
        int pos = atomicAdd(&lcnt[dl], 1);
        if (pos < ELLW) colELL[(size_t)(nbase + dl) * ELLW + pos] = s;
    }
    __syncthreads();
    for (int i = t; i < BINW; i += blockDim.x) {
        int node = nbase + i;
        if (node < n) {
            int c = lcnt[i];
            if (c > ELLW) c = ELLW;
            colELL[(size_t)node * ELLW + 0] = node;        // self edge
            int cpad = (c + 3) & ~3;
            for (int j = c; j < cpad; ++j)
                colELL[(size_t)node * ELLW + j] = n;       // dummy (h'[n] = 0)
            cnt[node] = c;                                  // deg+1
            dinv[node] = rsqrtf((float)c);
        }
    }
}

// One-time f32 -> f16 conversion of the three 64x64 weight matrices.
__global__ void prep_kernel(const float* __restrict__ W1, const float* __restrict__ W2,
                            const float* __restrict__ W3, unsigned short* __restrict__ w1h,
                            unsigned short* __restrict__ w2h, unsigned short* __restrict__ w3h) {
    int t = blockIdx.x * blockDim.x + threadIdx.x;
    if (t < NF * NF) {
        w1h[t] = f2h_u(W1[t]);
        w2h[t] = f2h_u(W2[t]);
        w3h[t] = f2h_u(W3[t]);
    }
}

// 8-deep gather step: accumulate up to cl4 staged edges of one row into acc[8].
// Two quads (8 loads) in flight per iteration; remainder one quad.
__device__ __forceinline__ void gather_row_mlp8(
        const unsigned short* __restrict__ hB, const int* __restrict__ cr,
        int cl4, int fq, float acc[8]) {
    int q = 0;
    for (; q + 8 <= cl4; q += 8) {
        int s0 = cr[q], s1 = cr[q + 1], s2 = cr[q + 2], s3 = cr[q + 3];
        int s4 = cr[q + 4], s5 = cr[q + 5], s6 = cr[q + 6], s7 = cr[q + 7];
        f16x8 h0 = *(const f16x8*)(hB + (size_t)s0 * NF + fq * 8);
        f16x8 h1 = *(const f16x8*)(hB + (size_t)s1 * NF + fq * 8);
        f16x8 h2 = *(const f16x8*)(hB + (size_t)s2 * NF + fq * 8);
        f16x8 h3 = *(const f16x8*)(hB + (size_t)s3 * NF + fq * 8);
        f16x8 h4 = *(const f16x8*)(hB + (size_t)s4 * NF + fq * 8);
        f16x8 h5 = *(const f16x8*)(hB + (size_t)s5 * NF + fq * 8);
        f16x8 h6 = *(const f16x8*)(hB + (size_t)s6 * NF + fq * 8);
        f16x8 h7 = *(const f16x8*)(hB + (size_t)s7 * NF + fq * 8);
        f16x8 ttA = (h0 + h1) + (h2 + h3);   // depth-2 f16 trees (per quad)
        f16x8 ttB = (h4 + h5) + (h6 + h7);
#pragma unroll
        for (int j = 0; j < 8; ++j) acc[j] += (float)ttA[j];
#pragma unroll
        for (int j = 0; j < 8; ++j) acc[j] += (float)ttB[j];
    }
    if (q + 4 <= cl4) {
        int s0 = cr[q], s1 = cr[q + 1], s2 = cr[q + 2], s3 = cr[q + 3];
        f16x8 h0 = *(const f16x8*)(hB + (size_t)s0 * NF + fq * 8);
        f16x8 h1 = *(const f16x8*)(hB + (size_t)s1 * NF + fq * 8);
        f16x8 h2 = *(const f16x8*)(hB + (size_t)s2 * NF + fq * 8);
        f16x8 h3 = *(const f16x8*)(hB + (size_t)s3 * NF + fq * 8);
        f16x8 tt = (h0 + h1) + (h2 + h3);
#pragma unroll
        for (int j = 0; j < 8; ++j) acc[j] += (float)tt[j];
    }
}

// ---- layer-1 MFMA GEMM: bufA = dinv * (x @ W1), f16 out via LDS repack ----
__device__ inline void load_W_frags(const unsigned short* __restrict__ Wh, int r16, int kq,
                                    f16x8 bfr[4][2]) {
#pragma unroll
    for (int nt = 0; nt < 4; ++nt)
#pragma unroll
        for (int kh = 0; kh < 2; ++kh) {
            f16x8 f;
#pragma unroll
            for (int j = 0; j < 8; ++j)
                f[j] = __builtin_bit_cast(_Float16,
                        Wh[(kh * 32 + kq * 8 + j) * NF + nt * 16 + r16]);
            bfr[nt][kh] = f;
        }
}

__global__ void __launch_bounds__(256) gemm1_mfma_kernel(const float* __restrict__ A,
                                                         const unsigned short* __restrict__ Wh,
                                                         const float* __restrict__ dinv,
                                                         unsigned short* __restrict__ outB, int n) {
    __shared__ unsigned short T[4][16 * LPITCH];
    int lane = threadIdx.x & 63;
    int r16 = lane & 15, kq = lane >> 4;
    int wv = threadIdx.x >> 6;
    int wid = blockIdx.x * 4 + wv;
    int nw = gridDim.x * 4;
    f16x8 bfr[4][2];
    load_W_frags(Wh, r16, kq, bfr);
    int ntiles = n >> 4;
    for (int t = wid; t < ntiles; t += nw) {
        int r0 = t << 4;
        const float* ar = A + (size_t)(r0 + r16) * NF + kq * 8;
        f16x8 a0, a1;
        float4 v0 = *(const float4*)(ar);
        float4 v1 = *(const float4*)(ar + 4);
        float4 v2 = *(const float4*)(ar + 32);
        float4 v3 = *(const float4*)(ar + 36);
        a0[0] = (_Float16)v0.x; a0[1] = (_Float16)v0.y;
        a0[2] = (_Float16)v0.z; a0[3] = (_Float16)v0.w;
        a0[4] = (_Float16)v1.x; a0[5] = (_Float16)v1.y;
        a0[6] = (_Float16)v1.z; a0[7] = (_Float16)v1.w;
        a1[0] = (_Float16)v2.x; a1[1] = (_Float16)v2.y;
        a1[2] = (_Float16)v2.z; a1[3] = (_Float16)v2.w;
        a1[4] = (_Float16)v3.x; a1[5] = (_Float16)v3.y;
        a1[6] = (_Float16)v3.z; a1[7] = (_Float16)v3.w;
        f32x4 acc[4];
#pragma unroll
        for (int nt = 0; nt < 4; ++nt) {
            acc[nt] = (f32x4)(0.0f);
            acc[nt] = __builtin_amdgcn_mfma_f32_16x16x32_f16(a0, bfr[nt][0], acc[nt], 0, 0, 0);
            acc[nt] = __builtin_amdgcn_mfma_f32_16x16x32_f16(a1, bfr[nt][1], acc[nt], 0, 0, 0);
        }
        float ds[4];
#pragma unroll
        for (int reg = 0; reg < 4; ++reg) ds[reg] = dinv[r0 + kq * 4 + reg];
        unsigned short* Tw = T[wv];
#pragma unroll
        for (int nt = 0; nt < 4; ++nt)
#pragma unroll
            for (int reg = 0; reg < 4; ++reg)
                Tw[(kq * 4 + reg) * LPITCH + nt * 16 + r16] = f2h_u(acc[nt][reg] * ds[reg]);
#pragma unroll
        for (int it = 0; it < 4; ++it) {
            int row = it * 4 + kq;
            uint2 v = *(const uint2*)&Tw[row * LPITCH + r16 * 4];
            *(uint2*)(outB + (size_t)(r0 + row) * NF + r16 * 4) = v;
        }
    }
}

// ---- fused: h = relu(dinv[d]*sum h'[s] + bias); out = dinv * (h @ W) ----
// Row-parallel gather, MLP-8. Block = 32 rows = 2 MFMA tiles; wave = 8 rows x
// 8 feature-octets. Each wave MFMAs tile (wv>>1), col slabs 2*(wv&1)+{0,1}.
__global__ void __launch_bounds__(256) fused_agg_gemm_kernel(
        const unsigned short* __restrict__ hB, const int* __restrict__ colELL,
        const int* __restrict__ cnt, const float* __restrict__ dinv,
        const float* __restrict__ bias, const unsigned short* __restrict__ Wh,
        unsigned short* __restrict__ outB, int n) {
    __shared__ int Icol[32 * 32];                    // 4KB: first 32 cols of 32 rows
    __shared__ int Icnt[32];
    __shared__ unsigned short Tin[2][2048];          // per tile: 16 rows x 64 feats, A-frag order
    __shared__ unsigned short Tout[2][16 * LPITCH];  // per tile C repack
    int t = threadIdx.x;
    int lane = t & 63;
    int wv = t >> 6;
    int es = lane >> 3;               // 0..7: row within wave's 8-row strip
    int fq = lane & 7;                // 0..7: feature octet
    int r16 = lane & 15, kq = lane >> 4;
    int r0 = (int)(blockIdx.x << 5);  // 32 rows per block
    {
        int srow = t >> 3, sj = t & 7;    // 256 threads = 32 rows x 8 int4
        ((int4*)Icol)[t] = *(const int4*)(colELL + (size_t)(r0 + srow) * ELLW + sj * 4);
    }
    if (t < 32) Icnt[t] = cnt[r0 + t];
    // W frags: wave wv covers col slabs s0 = 2*(wv&1), s0+1 (16 cols each)
    int s0 = (wv & 1) << 1;
    f16x8 bfr[2][2];
#pragma unroll
    for (int si = 0; si < 2; ++si)
#pragma unroll
        for (int kh = 0; kh < 2; ++kh) {
            f16x8 f;
#pragma unroll
            for (int j = 0; j < 8; ++j)
                f[j] = __builtin_bit_cast(_Float16,
                        Wh[(kh * 32 + kq * 8 + j) * NF + (s0 + si) * 16 + r16]);
            bfr[si][kh] = f;
        }
    __syncthreads();
    // ---- row-parallel gather, MLP-8 ----
    int lrow = wv * 8 + es;
    int row = r0 + lrow;
    int c = Icnt[lrow];
    int cpad = (c + 3) & ~3;
    int cl4 = cpad < 32 ? cpad : 32;
    const int* cr = Icol + lrow * 32;
    float acc[8];
#pragma unroll
    for (int j = 0; j < 8; ++j) acc[j] = 0.f;
    gather_row_mlp8(hB, cr, cl4, fq, acc);
    if (c > 32) {                      // rare tall row: global tail
        const int* crg = colELL + (size_t)row * ELLW;
        for (int qq = 32; qq + 4 <= cpad; qq += 4) {
            int s0e = crg[qq], s1e = crg[qq + 1], s2e = crg[qq + 2], s3e = crg[qq + 3];
            f16x8 h0 = *(const f16x8*)(hB + (size_t)s0e * NF + fq * 8);
            f16x8 h1 = *(const f16x8*)(hB + (size_t)s1e * NF + fq * 8);
            f16x8 h2 = *(const f16x8*)(hB + (size_t)s2e * NF + fq * 8);
            f16x8 h3 = *(const f16x8*)(hB + (size_t)s3e * NF + fq * 8);
            f16x8 tt = (h0 + h1) + (h2 + h3);
#pragma unroll
            for (int j = 0; j < 8; ++j) acc[j] += (float)tt[j];
        }
    }
    // epilogue: h = relu(dinv*acc + bias); write lane's A-frag slot
    {
        float dd = dinv[row];
        float4 bA = *(const float4*)(bias + fq * 8);
        float4 bB = *(const float4*)(bias + fq * 8 + 4);
        float r0f = fmaxf(dd * acc[0] + bA.x, 0.f), r1f = fmaxf(dd * acc[1] + bA.y, 0.f);
        float r2f = fmaxf(dd * acc[2] + bA.z, 0.f), r3f = fmaxf(dd * acc[3] + bA.w, 0.f);
        float r4f = fmaxf(dd * acc[4] + bB.x, 0.f), r5f = fmaxf(dd * acc[5] + bB.y, 0.f);
        float r6f = fmaxf(dd * acc[6] + bB.z, 0.f), r7f = fmaxf(dd * acc[7] + bB.w, 0.f);
        int4 v;
        v.x = (int)pack_h2(r0f, r1f);
        v.y = (int)pack_h2(r2f, r3f);
        v.z = (int)pack_h2(r4f, r5f);
        v.w = (int)pack_h2(r6f, r7f);
        int tile = lrow >> 4;
        int idx = ((fq >> 2) << 10) + (((fq & 3) * 16 + (lrow & 15)) << 3);
        *(int4*)&Tin[tile][idx] = v;
    }
    __syncthreads();
    // ---- MFMA: wave wv -> tile (wv>>1), slabs s0, s0+1 ----
    int tile = wv >> 1;
    f16x8 A0 = *(const f16x8*)&Tin[tile][lane * 8];
    f16x8 A1 = *(const f16x8*)&Tin[tile][1024 + lane * 8];
    float ds[4];
#pragma unroll
    for (int reg = 0; reg < 4; ++reg) ds[reg] = dinv[r0 + tile * 16 + kq * 4 + reg];
#pragma unroll
    for (int si = 0; si < 2; ++si) {
        f32x4 accC = (f32x4)(0.0f);
        accC = __builtin_amdgcn_mfma_f32_16x16x32_f16(A0, bfr[si][0], accC, 0, 0, 0);
        accC = __builtin_amdgcn_mfma_f32_16x16x32_f16(A1, bfr[si][1], accC, 0, 0, 0);
#pragma unroll
        for (int reg = 0; reg < 4; ++reg)
            Tout[tile][(kq * 4 + reg) * LPITCH + (s0 + si) * 16 + r16] =
                f2h_u(accC[reg] * ds[reg]);
    }
    __syncthreads();
    // store 32 rows x 64 feats
    {
        int orow = t >> 3, oc = t & 7;
        const unsigned short* p = &Tout[orow >> 4][(orow & 15) * LPITCH + oc * 8];
        uint2 v0 = *(const uint2*)(p);
        uint2 v1 = *(const uint2*)(p + 4);
        int4 v; v.x = (int)v0.x; v.y = (int)v0.y; v.z = (int)v1.x; v.w = (int)v1.y;
        *(int4*)(outB + (size_t)(r0 + orow) * NF + oc * 8) = v;
    }
}

// ---- layer-3 aggregation fused with mean-pool: row-parallel, MLP-8 ----
__global__ void __launch_bounds__(256) gather3_pool_kernel(
        const unsigned short* __restrict__ hB, const int* __restrict__ colELL,
        const int* __restrict__ cnt, const float* __restrict__ dinv,
        const float* __restrict__ bias, const int* __restrict__ batch,
        float* __restrict__ pooled, int n) {
    __shared__ int Icol[32 * 32];     // 4KB: first 32 cols of 32 rows
    __shared__ int Icnt[32];
    __shared__ int Ibatch[32];
    __shared__ float PL[2][NF];
    int t = threadIdx.x;
    int lane = t & 63;
    int wv = t >> 6;
    int es = lane >> 3;               // 0..7: row within wave
    int fq = lane & 7;                // 0..7: feature octet
    int r0 = (int)(blockIdx.x << 5);  // 32 rows per block (n % 32 == 0)
    {
        int srow = t >> 3, sj = t & 7;    // 256 threads = 32 rows x 8 int4
        ((int4*)Icol)[t] = *(const int4*)(colELL + (size_t)(r0 + srow) * ELLW + sj * 4);
    }
    if (t < 32) { Icnt[t] = cnt[r0 + t]; Ibatch[t] = batch[r0 + t]; }
    if (t >= 128) PL[(t - 128) >> 6][t & 63] = 0.f;
    __syncthreads();
    int lrow = wv * 8 + es;
    int row = r0 + lrow;
    int c = Icnt[lrow];
    int cpad = (c + 3) & ~3;          // >=4 (self edge), padded with dummies
    int cl4 = cpad < 32 ? cpad : 32;
    const int* cr = Icol + lrow * 32;
    float acc[8];
#pragma unroll
    for (int j = 0; j < 8; ++j) acc[j] = 0.f;
    gather_row_mlp8(hB, cr, cl4, fq, acc);
    if (c > 32) {                      // rare tall row: global tail, quads
        const int* crg = colELL + (size_t)row * ELLW;
        for (int qq = 32; qq + 4 <= cpad; qq += 4) {
            int s0 = crg[qq], s1 = crg[qq + 1], s2 = crg[qq + 2], s3 = crg[qq + 3];
            f16x8 h0 = *(const f16x8*)(hB + (size_t)s0 * NF + fq * 8);
            f16x8 h1 = *(const f16x8*)(hB + (size_t)s1 * NF + fq * 8);
            f16x8 h2 = *(const f16x8*)(hB + (size_t)s2 * NF + fq * 8);
            f16x8 h3 = *(const f16x8*)(hB + (size_t)s3 * NF + fq * 8);
            f16x8 tt = (h0 + h1) + (h2 + h3);
#pragma unroll
            for (int j = 0; j < 8; ++j) acc[j] += (float)tt[j];
        }
    }
    // epilogue: r = dinv*acc + bias (no relu), pool into LDS slots
    float dd = dinv[row];
    float4 bA = *(const float4*)(bias + fq * 8);
    float4 bB = *(const float4*)(bias + fq * 8 + 4);
    float r[8];
    r[0] = dd * acc[0] + bA.x; r[1] = dd * acc[1] + bA.y;
    r[2] = dd * acc[2] + bA.z; r[3] = dd * acc[3] + bA.w;
    r[4] = dd * acc[4] + bB.x; r[5] = dd * acc[5] + bB.y;
    r[6] = dd * acc[6] + bB.z; r[7] = dd * acc[7] + bB.w;
    int g = Ibatch[lrow];
    int gb = Ibatch[0];
    int sel = g - gb;
    if (sel < 2) {
#pragma unroll
        for (int j = 0; j < 8; ++j) atomicAdd(&PL[sel][fq * 8 + j], r[j]);
    } else {                           // window spans >2 graphs (improbable)
#pragma unroll
        for (int j = 0; j < 8; ++j) atomicAdd(&pooled[g * NF + fq * 8 + j], r[j]);
    }
    __syncthreads();
    if (t < 128) {
        int s = t >> 6, f = t & 63;
        float v = PL[s][f];
        if (v != 0.f) atomicAdd(&pooled[(gb + s) * NF + f], v);
    }
}

// counts[g] = #nodes in graph g (LDS histogram of batch)
__global__ void counts_kernel(const int* __restrict__ batch, float* __restrict__ counts, int n) {
    __shared__ int h[64];
    int t = threadIdx.x;
    if (t < 64) h[t] = 0;
    __syncthreads();
    for (int i = blockIdx.x * blockDim.x + t; i < n; i += gridDim.x * blockDim.x)
        atomicAdd(&h[batch[i]], 1);
    __syncthreads();
    if (t < 64 && h[t] > 0) atomicAdd(&counts[t], (float)h[t]);
}

// out[g][c] = (pooled[g][:]/max(cnt,1)) @ Wl[:,c] + bl[c]
__global__ void final_kernel(const float* __restrict__ pooled, const float* __restrict__ counts,
                             const float* __restrict__ Wl, const float* __restrict__ bl,
                             float* __restrict__ out) {
    int t = threadIdx.x;  // 128 threads: g = t>>1, c = t&1
    int g = t >> 1, c = t & 1;
    float inv = 1.0f / fmaxf(counts[g], 1.0f);
    float s = 0.0f;
#pragma unroll
    for (int j = 0; j < NF; ++j) s += pooled[g * NF + j] * Wl[j * 2 + c];
    out[t] = s * inv + bl[c];
}

extern "C" void kernel_launch(void* const* d_in, const int* in_sizes, int n_in,
                              void* d_out, int out_size, void* d_ws, size_t ws_size,
                              hipStream_t stream) {
    const float* x     = (const float*)d_in[0];
    const int*   ei    = (const int*)d_in[1];
    const int*   batch = (const int*)d_in[2];
    const float* W1    = (const float*)d_in[3];
    const float* b1    = (const float*)d_in[4];
    const float* W2    = (const float*)d_in[5];
    const float* b2    = (const float*)d_in[6];
    const float* W3    = (const float*)d_in[7];
    const float* b3    = (const float*)d_in[8];
    const float* Wl    = (const float*)d_in[9];
    const float* bl    = (const float*)d_in[10];
    float* out = (float*)d_out;

    const int n  = in_sizes[0] / NF;   // 100000 (divisible by 32)
    const int nE = in_sizes[1] / 2;    // 1600000
    const int* src = ei;
    const int* dst = ei + nE;

    // workspace layout (256B-aligned)
    char* ws = (char*)d_ws;
    auto alloc = [&](size_t bytes) {
        char* p = ws;
        ws += (bytes + 255) & ~(size_t)255;
        return p;
    };
    unsigned short* bufA = (unsigned short*)alloc((size_t)(n + 16) * NF * 2); // +dummy row
    unsigned short* bufB = (unsigned short*)alloc((size_t)(n + 16) * NF * 2);
    float* scratch = (float*)alloc((size_t)n * NF * 4);                  // binEdges alias
    int*   binEdges = (int*)scratch;                                     // build phase only (7.2 MB)
    int*   colELL = (int*)alloc((size_t)n * ELLW * 4);                   // 25.7 MB
    float* dinv   = (float*)alloc((size_t)(n + 16) * 4);                 // +dummy
    int*   cnt    = (int*)alloc((size_t)n * 4);
    unsigned short* w1h = (unsigned short*)alloc((size_t)NF * NF * 2);
    unsigned short* w2h = (unsigned short*)alloc((size_t)NF * NF * 2);
    unsigned short* w3h = (unsigned short*)alloc((size_t)NF * NF * 2);
    // zero-init tail: binCnt | pooled | counts (one memset)
    char*  ztail  = ws;
    int*   binCnt = (int*)alloc(NB * 4);
    float* pooled = (float*)alloc(64 * NF * 4);
    float* counts = (float*)alloc(64 * 4);
    size_t zbytes = (size_t)(ws - ztail);

    (void)hipMemsetAsync(ztail, 0, zbytes, stream);

    // ---- binned ELL build (once, reused by all 3 layers) ----
    const int chunk = 3200;
    binA_kernel<<<(nE + chunk - 1) / chunk, 256, 0, stream>>>(src, dst, binCnt, binEdges, nE, chunk);
    binB_kernel<<<NB, 512, 0, stream>>>(binEdges, binCnt, cnt, dinv, colELL, n,
                                        (unsigned int*)(bufA + (size_t)n * NF),
                                        (unsigned int*)(bufB + (size_t)n * NF));
    counts_kernel<<<98, 1024, 0, stream>>>(batch, counts, n);
    prep_kernel<<<16, 256, 0, stream>>>(W1, W2, W3, w1h, w2h, w3h);

    // conv1 GEMM: bufA = dinv * (x @ W1)
    gemm1_mfma_kernel<<<1563, 256, 0, stream>>>(x, w1h, dinv, bufA, n);
    // fused conv1-agg + conv2 GEMM: bufB = dinv * (relu(AGG'(bufA)+b1) @ W2)
    fused_agg_gemm_kernel<<<n >> 5, 256, 0, stream>>>(bufA, colELL, cnt, dinv, b1, w2h, bufB, n);
    // fused conv2-agg + conv3 GEMM: bufA = dinv * (relu(AGG'(bufB)+b2) @ W3)
    fused_agg_gemm_kernel<<<n >> 5, 256, 0, stream>>>(bufB, colELL, cnt, dinv, b2, w3h, bufA, n);
    // conv3 aggregation + mean-pool (row-parallel gather, 32 rows/block)
    gather3_pool_kernel<<<n >> 5, 256, 0, stream>>>(bufA, colELL, cnt, dinv, b3,
                                                    batch, pooled, n);

    final_kernel<<<1, 128, 0, stream>>>(pooled, counts, Wl, bl, out);
}

// Round 9
// 228.641 us; speedup vs baseline: 1.3315x; 1.0901x over previous
//
#include <hip/hip_runtime.h>

// GCN: 3x GCNConv(64->64) + global_mean_pool + linear(64->2)
// N=100000 nodes, E=1.6M edges, 64 graphs.
// Round 23: gather3_pool flush rework. The 8-per-thread LDS pool atomics
// (2048/block, 32-deep same-address chains -- the only kernel with nonzero
// SQ_LDS_BANK_CONFLICT) are replaced by a predicated butterfly reduce over
// es (strides 8/16/32); es==0 lanes accumulate into PL with chain depth <=4.
// Fast single-graph-wave path (99.5% of waves). Rest = r22.

#define NF 64
#define ELLW 64
#define BINSHIFT 9
#define BINW 512
#define NB 196         // ceil(100000 / 512)
#define BINCAP 9216    // per-bin edge cap: mean 8163 + ~11 sigma
#define LPITCH 68      // ushort pitch for C-repack LDS tile

typedef __attribute__((ext_vector_type(8))) _Float16 f16x8;  // 8 f16 (4 VGPRs)
typedef __attribute__((ext_vector_type(4))) _Float16 f16x4;  // 4 f16 (2 VGPRs)
typedef __attribute__((ext_vector_type(4))) float f32x4;     // 4 fp32 acc

__device__ inline unsigned short f2h_u(float f) {
    return __builtin_bit_cast(unsigned short, (_Float16)f);   // v_cvt_f16_f32 (RNE)
}
__device__ inline unsigned int pack_h2(float a, float b) {
    unsigned int ua = f2h_u(a), ub = f2h_u(b);
    return ua | (ub << 16);
}

// Phase A: partition edges by dst bin (LDS histogram, contiguous appends).
__global__ void binA_kernel(const int* __restrict__ src, const int* __restrict__ dst,
                            int* __restrict__ binCnt, int* __restrict__ binEdges,
                            int nE, int chunk) {
    __shared__ int hist[NB];
    __shared__ int base[NB];
    int t = threadIdx.x;
    if (t < NB) hist[t] = 0;
    __syncthreads();
    int e0 = blockIdx.x * chunk;
    int e1 = min(e0 + chunk, nE);
    for (int e = e0 + t; e < e1; e += blockDim.x) {
        int b = dst[e] >> BINSHIFT;
        atomicAdd(&hist[b], 1);
    }
    __syncthreads();
    if (t < NB) {
        base[t] = atomicAdd(&binCnt[t], hist[t]);
        hist[t] = 0;
    }
    __syncthreads();
    for (int e = e0 + t; e < e1; e += blockDim.x) {
        int d = dst[e];
        int b = d >> BINSHIFT;
        int pos = base[b] + atomicAdd(&hist[b], 1);
        if (pos < BINCAP)
            binEdges[(size_t)b * BINCAP + pos] = src[e] | ((d & (BINW - 1)) << 17);
    }
}

// Phase B: one block per bin; ELL slot 0 = self edge; rows padded to multiple
// of 4 with dummy index n (h'[n] = 0). Block 0 zeroes dummy feature rows.
__global__ void __launch_bounds__(512) binB_kernel(const int* __restrict__ binEdges,
                            const int* __restrict__ binCnt, int* __restrict__ cnt,
                            float* __restrict__ dinv, int* __restrict__ colELL, int n,
                            unsigned int* __restrict__ dummyA, unsigned int* __restrict__ dummyB) {
    __shared__ int lcnt[BINW];
    int t = threadIdx.x;
    int b = blockIdx.x;
    if (b == 0 && t < 32) { dummyA[t] = 0u; dummyB[t] = 0u; }   // h'[n] = 0 (128B each)
    for (int i = t; i < BINW; i += blockDim.x) lcnt[i] = 1;   // slot 0 = self
    __syncthreads();
    int m = binCnt[b];
    if (m > BINCAP) m = BINCAP;
    const int* be = binEdges + (size_t)b * BINCAP;
    int nbase = b << BINSHIFT;
    for (int e = t; e < m; e += blockDim.x) {
        int v = be[e];
        int s = v & 0x1FFFF;
        int dl = v >> 17;
        int pos = atomicAdd(&lcnt[dl], 1);
        if (pos < ELLW) colELL[(size_t)(nbase + dl) * ELLW + pos] = s;
    }
    __syncthreads();
    for (int i = t; i < BINW; i += blockDim.x) {
        int node = nbase + i;
        if (node < n) {
            int c = lcnt[i];
            if (c > ELLW) c = ELLW;
            colELL[(size_t)node * ELLW + 0] = node;        // self edge
            int cpad = (c + 3) & ~3;
            for (int j = c; j < cpad; ++j)
                colELL[(size_t)node * ELLW + j] = n;       // dummy (h'[n] = 0)
            cnt[node] = c;                                  // deg+1
            dinv[node] = rsqrtf((float)c);
        }
    }
}

// One-time f32 -> f16 conversion of the three 64x64 weight matrices.
__global__ void prep_kernel(const float* __restrict__ W1, const float* __restrict__ W2,
                            const float* __restrict__ W3, unsigned short* __restrict__ w1h,
                            unsigned short* __restrict__ w2h, unsigned short* __restrict__ w3h) {
    int t = blockIdx.x * blockDim.x + threadIdx.x;
    if (t < NF * NF) {
        w1h[t] = f2h_u(W1[t]);
        w2h[t] = f2h_u(W2[t]);
        w3h[t] = f2h_u(W3[t]);
    }
}

// 8-deep gather step: accumulate up to cl4 staged edges of one row into acc[8].
// Two quads (8 loads) in flight per iteration; remainder one quad.
__device__ __forceinline__ void gather_row_mlp8(
        const unsigned short* __restrict__ hB, const int* __restrict__ cr,
        int cl4, int fq, float acc[8]) {
    int q = 0;
    for (; q + 8 <= cl4; q += 8) {
        int s0 = cr[q], s1 = cr[q + 1], s2 = cr[q + 2], s3 = cr[q + 3];
        int s4 = cr[q + 4], s5 = cr[q + 5], s6 = cr[q + 6], s7 = cr[q + 7];
        f16x8 h0 = *(const f16x8*)(hB + (size_t)s0 * NF + fq * 8);
        f16x8 h1 = *(const f16x8*)(hB + (size_t)s1 * NF + fq * 8);
        f16x8 h2 = *(const f16x8*)(hB + (size_t)s2 * NF + fq * 8);
        f16x8 h3 = *(const f16x8*)(hB + (size_t)s3 * NF + fq * 8);
        f16x8 h4 = *(const f16x8*)(hB + (size_t)s4 * NF + fq * 8);
        f16x8 h5 = *(const f16x8*)(hB + (size_t)s5 * NF + fq * 8);
        f16x8 h6 = *(const f16x8*)(hB + (size_t)s6 * NF + fq * 8);
        f16x8 h7 = *(const f16x8*)(hB + (size_t)s7 * NF + fq * 8);
        f16x8 ttA = (h0 + h1) + (h2 + h3);   // depth-2 f16 trees (per quad)
        f16x8 ttB = (h4 + h5) + (h6 + h7);
#pragma unroll
        for (int j = 0; j < 8; ++j) acc[j] += (float)ttA[j];
#pragma unroll
        for (int j = 0; j < 8; ++j) acc[j] += (float)ttB[j];
    }
    if (q + 4 <= cl4) {
        int s0 = cr[q], s1 = cr[q + 1], s2 = cr[q + 2], s3 = cr[q + 3];
        f16x8 h0 = *(const f16x8*)(hB + (size_t)s0 * NF + fq * 8);
        f16x8 h1 = *(const f16x8*)(hB + (size_t)s1 * NF + fq * 8);
        f16x8 h2 = *(const f16x8*)(hB + (size_t)s2 * NF + fq * 8);
        f16x8 h3 = *(const f16x8*)(hB + (size_t)s3 * NF + fq * 8);
        f16x8 tt = (h0 + h1) + (h2 + h3);
#pragma unroll
        for (int j = 0; j < 8; ++j) acc[j] += (float)tt[j];
    }
}

// ---- layer-1 MFMA GEMM: bufA = dinv * (x @ W1), f16 out via LDS repack ----
__device__ inline void load_W_frags(const unsigned short* __restrict__ Wh, int r16, int kq,
                                    f16x8 bfr[4][2]) {
#pragma unroll
    for (int nt = 0; nt < 4; ++nt)
#pragma unroll
        for (int kh = 0; kh < 2; ++kh) {
            f16x8 f;
#pragma unroll
            for (int j = 0; j < 8; ++j)
                f[j] = __builtin_bit_cast(_Float16,
                        Wh[(kh * 32 + kq * 8 + j) * NF + nt * 16 + r16]);
            bfr[nt][kh] = f;
        }
}

__global__ void __launch_bounds__(256) gemm1_mfma_kernel(const float* __restrict__ A,
                                                         const unsigned short* __restrict__ Wh,
                                                         const float* __restrict__ dinv,
                                                         unsigned short* __restrict__ outB, int n) {
    __shared__ unsigned short T[4][16 * LPITCH];
    int lane = threadIdx.x & 63;
    int r16 = lane & 15, kq = lane >> 4;
    int wv = threadIdx.x >> 6;
    int wid = blockIdx.x * 4 + wv;
    int nw = gridDim.x * 4;
    f16x8 bfr[4][2];
    load_W_frags(Wh, r16, kq, bfr);
    int ntiles = n >> 4;
    for (int t = wid; t < ntiles; t += nw) {
        int r0 = t << 4;
        const float* ar = A + (size_t)(r0 + r16) * NF + kq * 8;
        f16x8 a0, a1;
        float4 v0 = *(const float4*)(ar);
        float4 v1 = *(const float4*)(ar + 4);
        float4 v2 = *(const float4*)(ar + 32);
        float4 v3 = *(const float4*)(ar + 36);
        a0[0] = (_Float16)v0.x; a0[1] = (_Float16)v0.y;
        a0[2] = (_Float16)v0.z; a0[3] = (_Float16)v0.w;
        a0[4] = (_Float16)v1.x; a0[5] = (_Float16)v1.y;
        a0[6] = (_Float16)v1.z; a0[7] = (_Float16)v1.w;
        a1[0] = (_Float16)v2.x; a1[1] = (_Float16)v2.y;
        a1[2] = (_Float16)v2.z; a1[3] = (_Float16)v2.w;
        a1[4] = (_Float16)v3.x; a1[5] = (_Float16)v3.y;
        a1[6] = (_Float16)v3.z; a1[7] = (_Float16)v3.w;
        f32x4 acc[4];
#pragma unroll
        for (int nt = 0; nt < 4; ++nt) {
            acc[nt] = (f32x4)(0.0f);
            acc[nt] = __builtin_amdgcn_mfma_f32_16x16x32_f16(a0, bfr[nt][0], acc[nt], 0, 0, 0);
            acc[nt] = __builtin_amdgcn_mfma_f32_16x16x32_f16(a1, bfr[nt][1], acc[nt], 0, 0, 0);
        }
        float ds[4];
#pragma unroll
        for (int reg = 0; reg < 4; ++reg) ds[reg] = dinv[r0 + kq * 4 + reg];
        unsigned short* Tw = T[wv];
#pragma unroll
        for (int nt = 0; nt < 4; ++nt)
#pragma unroll
            for (int reg = 0; reg < 4; ++reg)
                Tw[(kq * 4 + reg) * LPITCH + nt * 16 + r16] = f2h_u(acc[nt][reg] * ds[reg]);
#pragma unroll
        for (int it = 0; it < 4; ++it) {
            int row = it * 4 + kq;
            uint2 v = *(const uint2*)&Tw[row * LPITCH + r16 * 4];
            *(uint2*)(outB + (size_t)(r0 + row) * NF + r16 * 4) = v;
        }
    }
}

// ---- fused: h = relu(dinv[d]*sum h'[s] + bias); out = dinv * (h @ W) ----
// Row-parallel gather, MLP-8. Block = 32 rows = 2 MFMA tiles; wave = 8 rows x
// 8 feature-octets. Each wave MFMAs tile (wv>>1), col slabs 2*(wv&1)+{0,1}.
__global__ void __launch_bounds__(256) fused_agg_gemm_kernel(
        const unsigned short* __restrict__ hB, const int* __restrict__ colELL,
        const int* __restrict__ cnt, const float* __restrict__ dinv,
        const float* __restrict__ bias, const unsigned short* __restrict__ Wh,
        unsigned short* __restrict__ outB, int n) {
    __shared__ int Icol[32 * 32];                    // 4KB: first 32 cols of 32 rows
    __shared__ int Icnt[32];
    __shared__ unsigned short Tin[2][2048];          // per tile: 16 rows x 64 feats, A-frag order
    __shared__ unsigned short Tout[2][16 * LPITCH];  // per tile C repack
    int t = threadIdx.x;
    int lane = t & 63;
    int wv = t >> 6;
    int es = lane >> 3;               // 0..7: row within wave's 8-row strip
    int fq = lane & 7;                // 0..7: feature octet
    int r16 = lane & 15, kq = lane >> 4;
    int r0 = (int)(blockIdx.x << 5);  // 32 rows per block
    {
        int srow = t >> 3, sj = t & 7;    // 256 threads = 32 rows x 8 int4
        ((int4*)Icol)[t] = *(const int4*)(colELL + (size_t)(r0 + srow) * ELLW + sj * 4);
    }
    if (t < 32) Icnt[t] = cnt[r0 + t];
    // W frags: wave wv covers col slabs s0 = 2*(wv&1), s0+1 (16 cols each)
    int s0 = (wv & 1) << 1;
    f16x8 bfr[2][2];
#pragma unroll
    for (int si = 0; si < 2; ++si)
#pragma unroll
        for (int kh = 0; kh < 2; ++kh) {
            f16x8 f;
#pragma unroll
            for (int j = 0; j < 8; ++j)
                f[j] = __builtin_bit_cast(_Float16,
                        Wh[(kh * 32 + kq * 8 + j) * NF + (s0 + si) * 16 + r16]);
            bfr[si][kh] = f;
        }
    __syncthreads();
    // ---- row-parallel gather, MLP-8 ----
    int lrow = wv * 8 + es;
    int row = r0 + lrow;
    int c = Icnt[lrow];
    int cpad = (c + 3) & ~3;
    int cl4 = cpad < 32 ? cpad : 32;
    const int* cr = Icol + lrow * 32;
    float acc[8];
#pragma unroll
    for (int j = 0; j < 8; ++j) acc[j] = 0.f;
    gather_row_mlp8(hB, cr, cl4, fq, acc);
    if (c > 32) {                      // rare tall row: global tail
        const int* crg = colELL + (size_t)row * ELLW;
        for (int qq = 32; qq + 4 <= cpad; qq += 4) {
            int s0e = crg[qq], s1e = crg[qq + 1], s2e = crg[qq + 2], s3e = crg[qq + 3];
            f16x8 h0 = *(const f16x8*)(hB + (size_t)s0e * NF + fq * 8);
            f16x8 h1 = *(const f16x8*)(hB + (size_t)s1e * NF + fq * 8);
            f16x8 h2 = *(const f16x8*)(hB + (size_t)s2e * NF + fq * 8);
            f16x8 h3 = *(const f16x8*)(hB + (size_t)s3e * NF + fq * 8);
            f16x8 tt = (h0 + h1) + (h2 + h3);
#pragma unroll
            for (int j = 0; j < 8; ++j) acc[j] += (float)tt[j];
        }
    }
    // epilogue: h = relu(dinv*acc + bias); write lane's A-frag slot
    {
        float dd = dinv[row];
        float4 bA = *(const float4*)(bias + fq * 8);
        float4 bB = *(const float4*)(bias + fq * 8 + 4);
        float r0f = fmaxf(dd * acc[0] + bA.x, 0.f), r1f = fmaxf(dd * acc[1] + bA.y, 0.f);
        float r2f = fmaxf(dd * acc[2] + bA.z, 0.f), r3f = fmaxf(dd * acc[3] + bA.w, 0.f);
        float r4f = fmaxf(dd * acc[4] + bB.x, 0.f), r5f = fmaxf(dd * acc[5] + bB.y, 0.f);
        float r6f = fmaxf(dd * acc[6] + bB.z, 0.f), r7f = fmaxf(dd * acc[7] + bB.w, 0.f);
        int4 v;
        v.x = (int)pack_h2(r0f, r1f);
        v.y = (int)pack_h2(r2f, r3f);
        v.z = (int)pack_h2(r4f, r5f);
        v.w = (int)pack_h2(r6f, r7f);
        int tile = lrow >> 4;
        int idx = ((fq >> 2) << 10) + (((fq & 3) * 16 + (lrow & 15)) << 3);
        *(int4*)&Tin[tile][idx] = v;
    }
    __syncthreads();
    // ---- MFMA: wave wv -> tile (wv>>1), slabs s0, s0+1 ----
    int tile = wv >> 1;
    f16x8 A0 = *(const f16x8*)&Tin[tile][lane * 8];
    f16x8 A1 = *(const f16x8*)&Tin[tile][1024 + lane * 8];
    float ds[4];
#pragma unroll
    for (int reg = 0; reg < 4; ++reg) ds[reg] = dinv[r0 + tile * 16 + kq * 4 + reg];
#pragma unroll
    for (int si = 0; si < 2; ++si) {
        f32x4 accC = (f32x4)(0.0f);
        accC = __builtin_amdgcn_mfma_f32_16x16x32_f16(A0, bfr[si][0], accC, 0, 0, 0);
        accC = __builtin_amdgcn_mfma_f32_16x16x32_f16(A1, bfr[si][1], accC, 0, 0, 0);
#pragma unroll
        for (int reg = 0; reg < 4; ++reg)
            Tout[tile][(kq * 4 + reg) * LPITCH + (s0 + si) * 16 + r16] =
                f2h_u(accC[reg] * ds[reg]);
    }
    __syncthreads();
    // store 32 rows x 64 feats
    {
        int orow = t >> 3, oc = t & 7;
        const unsigned short* p = &Tout[orow >> 4][(orow & 15) * LPITCH + oc * 8];
        uint2 v0 = *(const uint2*)(p);
        uint2 v1 = *(const uint2*)(p + 4);
        int4 v; v.x = (int)v0.x; v.y = (int)v0.y; v.z = (int)v1.x; v.w = (int)v1.y;
        *(int4*)(outB + (size_t)(r0 + orow) * NF + oc * 8) = v;
    }
}

// ---- layer-3 aggregation fused with mean-pool: row-parallel, MLP-8 ----
// Pool flush via predicated butterfly reduce over es (strides 8/16/32);
// es==0 lanes accumulate into PL (chain depth <= 4 waves).
__global__ void __launch_bounds__(256) gather3_pool_kernel(
        const unsigned short* __restrict__ hB, const int* __restrict__ colELL,
        const int* __restrict__ cnt, const float* __restrict__ dinv,
        const float* __restrict__ bias, const int* __restrict__ batch,
        float* __restrict__ pooled, int n) {
    __shared__ int Icol[32 * 32];     // 4KB: first 32 cols of 32 rows
    __shared__ int Icnt[32];
    __shared__ int Ibatch[32];
    __shared__ float PL[2][NF];
    int t = threadIdx.x;
    int lane = t & 63;
    int wv = t >> 6;
    int es = lane >> 3;               // 0..7: row within wave
    int fq = lane & 7;                // 0..7: feature octet
    int r0 = (int)(blockIdx.x << 5);  // 32 rows per block (n % 32 == 0)
    {
        int srow = t >> 3, sj = t & 7;    // 256 threads = 32 rows x 8 int4
        ((int4*)Icol)[t] = *(const int4*)(colELL + (size_t)(r0 + srow) * ELLW + sj * 4);
    }
    if (t < 32) { Icnt[t] = cnt[r0 + t]; Ibatch[t] = batch[r0 + t]; }
    if (t >= 128) PL[(t - 128) >> 6][t & 63] = 0.f;
    __syncthreads();
    int lrow = wv * 8 + es;
    int row = r0 + lrow;
    int c = Icnt[lrow];
    int cpad = (c + 3) & ~3;          // >=4 (self edge), padded with dummies
    int cl4 = cpad < 32 ? cpad : 32;
    const int* cr = Icol + lrow * 32;
    float acc[8];
#pragma unroll
    for (int j = 0; j < 8; ++j) acc[j] = 0.f;
    gather_row_mlp8(hB, cr, cl4, fq, acc);
    if (c > 32) {                      // rare tall row: global tail, quads
        const int* crg = colELL + (size_t)row * ELLW;
        for (int qq = 32; qq + 4 <= cpad; qq += 4) {
            int s0 = crg[qq], s1 = crg[qq + 1], s2 = crg[qq + 2], s3 = crg[qq + 3];
            f16x8 h0 = *(const f16x8*)(hB + (size_t)s0 * NF + fq * 8);
            f16x8 h1 = *(const f16x8*)(hB + (size_t)s1 * NF + fq * 8);
            f16x8 h2 = *(const f16x8*)(hB + (size_t)s2 * NF + fq * 8);
            f16x8 h3 = *(const f16x8*)(hB + (size_t)s3 * NF + fq * 8);
            f16x8 tt = (h0 + h1) + (h2 + h3);
#pragma unroll
            for (int j = 0; j < 8; ++j) acc[j] += (float)tt[j];
        }
    }
    // epilogue: r = dinv*acc + bias (no relu)
    float dd = dinv[row];
    float4 bA = *(const float4*)(bias + fq * 8);
    float4 bB = *(const float4*)(bias + fq * 8 + 4);
    float r[8];
    r[0] = dd * acc[0] + bA.x; r[1] = dd * acc[1] + bA.y;
    r[2] = dd * acc[2] + bA.z; r[3] = dd * acc[3] + bA.w;
    r[4] = dd * acc[4] + bB.x; r[5] = dd * acc[5] + bB.y;
    r[6] = dd * acc[6] + bB.z; r[7] = dd * acc[7] + bB.w;
    int g = Ibatch[lrow];
    int gb = Ibatch[0];
    int sel = g - gb;
    // ---- pool: butterfly reduce over es, then es==0 lanes hit PL ----
    unsigned long long one_graph = __ballot(sel == 0);
    if (one_graph == ~0ULL) {         // whole wave in graph gb (99.5% of waves)
#pragma unroll
        for (int j = 0; j < 8; ++j) {
            float v = r[j];
            v += __shfl_xor(v, 8);
            v += __shfl_xor(v, 16);
            v += __shfl_xor(v, 32);
            if (es == 0) atomicAdd(&PL[0][fq * 8 + j], v);
        }
    } else {                          // boundary wave: 2-slot predicated trees
#pragma unroll
        for (int j = 0; j < 8; ++j) {
            float v0 = sel == 0 ? r[j] : 0.f;
            float v1 = sel == 1 ? r[j] : 0.f;
            v0 += __shfl_xor(v0, 8);  v1 += __shfl_xor(v1, 8);
            v0 += __shfl_xor(v0, 16); v1 += __shfl_xor(v1, 16);
            v0 += __shfl_xor(v0, 32); v1 += __shfl_xor(v1, 32);
            if (es == 0) {
                atomicAdd(&PL[0][fq * 8 + j], v0);
                atomicAdd(&PL[1][fq * 8 + j], v1);
            }
            if (sel >= 2)             // improbable >2-graph window: direct global
                atomicAdd(&pooled[g * NF + fq * 8 + j], r[j]);
        }
    }
    __syncthreads();
    if (t < 128) {
        int s = t >> 6, f = t & 63;
        float v = PL[s][f];
        if (v != 0.f) atomicAdd(&pooled[(gb + s) * NF + f], v);
    }
}

// counts[g] = #nodes in graph g (LDS histogram of batch)
__global__ void counts_kernel(const int* __restrict__ batch, float* __restrict__ counts, int n) {
    __shared__ int h[64];
    int t = threadIdx.x;
    if (t < 64) h[t] = 0;
    __syncthreads();
    for (int i = blockIdx.x * blockDim.x + t; i < n; i += gridDim.x * blockDim.x)
        atomicAdd(&h[batch[i]], 1);
    __syncthreads();
    if (t < 64 && h[t] > 0) atomicAdd(&counts[t], (float)h[t]);
}

// out[g][c] = (pooled[g][:]/max(cnt,1)) @ Wl[:,c] + bl[c]
__global__ void final_kernel(const float* __restrict__ pooled, const float* __restrict__ counts,
                             const float* __restrict__ Wl, const float* __restrict__ bl,
                             float* __restrict__ out) {
    int t = threadIdx.x;  // 128 threads: g = t>>1, c = t&1
    int g = t >> 1, c = t & 1;
    float inv = 1.0f / fmaxf(counts[g], 1.0f);
    float s = 0.0f;
#pragma unroll
    for (int j = 0; j < NF; ++j) s += pooled[g * NF + j] * Wl[j * 2 + c];
    out[t] = s * inv + bl[c];
}

extern "C" void kernel_launch(void* const* d_in, const int* in_sizes, int n_in,
                              void* d_out, int out_size, void* d_ws, size_t ws_size,
                              hipStream_t stream) {
    const float* x     = (const float*)d_in[0];
    const int*   ei    = (const int*)d_in[1];
    const int*   batch = (const int*)d_in[2];
    const float* W1    = (const float*)d_in[3];
    const float* b1    = (const float*)d_in[4];
    const float* W2    = (const float*)d_in[5];
    const float* b2    = (const float*)d_in[6];
    const float* W3    = (const float*)d_in[7];
    const float* b3    = (const float*)d_in[8];
    const float* Wl    = (const float*)d_in[9];
    const float* bl    = (const float*)d_in[10];
    float* out = (float*)d_out;

    const int n  = in_sizes[0] / NF;   // 100000 (divisible by 32)
    const int nE = in_sizes[1] / 2;    // 1600000
    const int* src = ei;
    const int* dst = ei + nE;

    // workspace layout (256B-aligned)
    char* ws = (char*)d_ws;
    auto alloc = [&](size_t bytes) {
        char* p = ws;
        ws += (bytes + 255) & ~(size_t)255;
        return p;
    };
    unsigned short* bufA = (unsigned short*)alloc((size_t)(n + 16) * NF * 2); // +dummy row
    unsigned short* bufB = (unsigned short*)alloc((size_t)(n + 16) * NF * 2);
    float* scratch = (float*)alloc((size_t)n * NF * 4);                  // binEdges alias
    int*   binEdges = (int*)scratch;                                     // build phase only (7.2 MB)
    int*   colELL = (int*)alloc((size_t)n * ELLW * 4);                   // 25.7 MB
    float* dinv   = (float*)alloc((size_t)(n + 16) * 4);                 // +dummy
    int*   cnt    = (int*)alloc((size_t)n * 4);
    unsigned short* w1h = (unsigned short*)alloc((size_t)NF * NF * 2);
    unsigned short* w2h = (unsigned short*)alloc((size_t)NF * NF * 2);
    unsigned short* w3h = (unsigned short*)alloc((size_t)NF * NF * 2);
    // zero-init tail: binCnt | pooled | counts (one memset)
    char*  ztail  = ws;
    int*   binCnt = (int*)alloc(NB * 4);
    float* pooled = (float*)alloc(64 * NF * 4);
    float* counts = (float*)alloc(64 * 4);
    size_t zbytes = (size_t)(ws - ztail);

    (void)hipMemsetAsync(ztail, 0, zbytes, stream);

    // ---- binned ELL build (once, reused by all 3 layers) ----
    const int chunk = 3200;
    binA_kernel<<<(nE + chunk - 1) / chunk, 256, 0, stream>>>(src, dst, binCnt, binEdges, nE, chunk);
    binB_kernel<<<NB, 512, 0, stream>>>(binEdges, binCnt, cnt, dinv, colELL, n,
                                        (unsigned int*)(bufA + (size_t)n * NF),
                                        (unsigned int*)(bufB + (size_t)n * NF));
    counts_kernel<<<98, 1024, 0, stream>>>(batch, counts, n);
    prep_kernel<<<16, 256, 0, stream>>>(W1, W2, W3, w1h, w2h, w3h);

    // conv1 GEMM: bufA = dinv * (x @ W1)
    gemm1_mfma_kernel<<<1563, 256, 0, stream>>>(x, w1h, dinv, bufA, n);
    // fused conv1-agg + conv2 GEMM: bufB = dinv * (relu(AGG'(bufA)+b1) @ W2)
    fused_agg_gemm_kernel<<<n >> 5, 256, 0, stream>>>(bufA, colELL, cnt, dinv, b1, w2h, bufB, n);
    // fused conv2-agg + conv3 GEMM: bufA = dinv * (relu(AGG'(bufB)+b2) @ W3)
    fused_agg_gemm_kernel<<<n >> 5, 256, 0, stream>>>(bufB, colELL, cnt, dinv, b2, w3h, bufA, n);
    // conv3 aggregation + mean-pool (row-parallel gather, 32 rows/block)
    gather3_pool_kernel<<<n >> 5, 256, 0, stream>>>(bufA, colELL, cnt, dinv, b3,
                                                    batch, pooled, n);

    final_kernel<<<1, 128, 0, stream>>>(pooled, counts, Wl, bl, out);
}